// Round 1
// baseline (1066.311 us; speedup 1.0000x reference)
//
#include <hip/hip_runtime.h>
#include <cstdint>
#include <cmath>

typedef __attribute__((ext_vector_type(4))) float floatx4;
typedef __attribute__((ext_vector_type(8))) __bf16 bf16x8;
typedef __attribute__((ext_vector_type(4))) unsigned short ushort4v;

#define DEVI static __device__ __forceinline__

DEVI unsigned short f2b(float f) {
    unsigned x = __float_as_uint(f);
    return (unsigned short)((x + 0x7fffu + ((x >> 16) & 1u)) >> 16);
}
DEVI float b2f(unsigned short u) { return __uint_as_float(((unsigned)u) << 16); }

// async global->LDS, 16B per lane; LDS dest is wave-uniform base + lane*16
DEVI void load16(void* lds, const void* g) {
    __builtin_amdgcn_global_load_lds(
        (__attribute__((address_space(1))) void*)(const_cast<void*>(g)),
        (__attribute__((address_space(3))) void*)lds, 16, 0, 0);
}

// ---------------------------------------------------------------------------
// fp32 -> bf16 convert (vector x4)
// ---------------------------------------------------------------------------
__global__ __launch_bounds__(256) void cvt_kernel(const float* __restrict__ src,
                                                  unsigned short* __restrict__ dst, int n4) {
    int i = blockIdx.x * 256 + threadIdx.x;
    if (i >= n4) return;
    floatx4 v = ((const floatx4*)src)[i];
    ushort4v o;
    o[0] = f2b(v[0]); o[1] = f2b(v[1]); o[2] = f2b(v[2]); o[3] = f2b(v[3]);
    ((ushort4v*)dst)[i] = o;
}

__global__ __launch_bounds__(256) void catbias_kernel(const float* __restrict__ a,
                                                      const float* __restrict__ b,
                                                      const float* __restrict__ c,
                                                      const float* __restrict__ d,
                                                      float* __restrict__ o) {
    int i = blockIdx.x * 256 + threadIdx.x;   // 4096 total
    int p = i >> 10, j = i & 1023;
    float v = (p == 0) ? a[j] : (p == 1) ? b[j] : (p == 2) ? c[j] : d[j];
    o[i] = v;
}

// ---------------------------------------------------------------------------
// LayerNorm over D=1024: one block per row, optional bf16 and fp32 outputs
// ---------------------------------------------------------------------------
__global__ __launch_bounds__(256) void ln_kernel(const float* __restrict__ in,
                                                 const float* __restrict__ w,
                                                 const float* __restrict__ b,
                                                 unsigned short* __restrict__ obf,
                                                 float* __restrict__ of) {
    const int row = blockIdx.x, tid = threadIdx.x;
    const floatx4* pr = (const floatx4*)(in + (size_t)row * 1024);
    floatx4 v = pr[tid];
    float s  = v[0] + v[1] + v[2] + v[3];
    float ss = v[0]*v[0] + v[1]*v[1] + v[2]*v[2] + v[3]*v[3];
    #pragma unroll
    for (int o = 32; o >= 1; o >>= 1) { s += __shfl_xor(s, o); ss += __shfl_xor(ss, o); }
    __shared__ float red[8];
    int wv = tid >> 6, lane = tid & 63;
    if (lane == 0) { red[wv] = s; red[4 + wv] = ss; }
    __syncthreads();
    s  = red[0] + red[1] + red[2] + red[3];
    ss = red[4] + red[5] + red[6] + red[7];
    float mu  = s * (1.0f / 1024.0f);
    float var = ss * (1.0f / 1024.0f) - mu * mu;
    float rstd = rsqrtf(var + 1e-5f);
    floatx4 wv4 = ((const floatx4*)w)[tid];
    floatx4 bv4 = ((const floatx4*)b)[tid];
    floatx4 o;
    #pragma unroll
    for (int c = 0; c < 4; c++) o[c] = (v[c] - mu) * rstd * wv4[c] + bv4[c];
    if (obf) {
        ushort4v t;
        t[0] = f2b(o[0]); t[1] = f2b(o[1]); t[2] = f2b(o[2]); t[3] = f2b(o[3]);
        ((ushort4v*)(obf + (size_t)row * 1024))[tid] = t;
    }
    if (of) ((floatx4*)(of + (size_t)row * 1024))[tid] = o;
}

// ---------------------------------------------------------------------------
// INL integrator: 5 explicit steps in registers, then x2 = x1 + xs -> d_out
// ---------------------------------------------------------------------------
__global__ __launch_bounds__(256) void integrator_kernel(const float* __restrict__ xs0,
                                                         const unsigned short* __restrict__ uabg,
                                                         float* __restrict__ xio) {
    size_t i = (size_t)blockIdx.x * 256 + threadIdx.x;  // group of 4 elems
    size_t tok = i >> 8;
    int grp = (int)(i & 255) * 4;
    const unsigned short* ubase = uabg + tok * 4096 + grp;
    ushort4v uu = *(const ushort4v*)(ubase);
    ushort4v aa = *(const ushort4v*)(ubase + 1024);
    ushort4v bb = *(const ushort4v*)(ubase + 2048);
    ushort4v gg = *(const ushort4v*)(ubase + 3072);
    floatx4 xsv = ((const floatx4*)xs0)[i];
    floatx4 x1  = ((const floatx4*)xio)[i];
    floatx4 res;
    #pragma unroll
    for (int c = 0; c < 4; c++) {
        float u = b2f(uu[c]), a = b2f(aa[c]), bt = b2f(bb[c]), g = b2f(gg[c]);
        float xs = xsv[c], vs = 0.f;
        #pragma unroll
        for (int t = 0; t < 5; t++) {
            vs += 0.1f * (-a * xs - bt * vs + u);
            xs += 0.1f * g * vs;
        }
        res[c] = x1[c] + xs;
    }
    ((floatx4*)xio)[i] = res;
}

// ---------------------------------------------------------------------------
// bf16 GEMM: C[M,N] = A[M,K] @ W[N,K]^T (+bias) with fused epilogues.
// 128x128 tile, BK=32, 4 waves (2x2 of 64x64), 16x16x32 MFMA, m97 staging.
// EPI: 0=QKV scatter  1=out-proj(+residual,+ctx)  2=INL activations
//      3=FF1 GELU     4=FF2 accumulate into d_out
// ---------------------------------------------------------------------------
template <int EPI>
__global__ __launch_bounds__(256) void gemm_bt(const unsigned short* __restrict__ A,
                                               const unsigned short* __restrict__ W,
                                               const float* __restrict__ bias, int K,
                                               unsigned short* __restrict__ ob0,
                                               unsigned short* __restrict__ ob1,
                                               unsigned short* __restrict__ ob2,
                                               float* __restrict__ of0,
                                               const float* __restrict__ xres) {
    __shared__ unsigned short sA[128 * 32];
    __shared__ unsigned short sB[128 * 32];
    const int tid = threadIdx.x;
    const int wave = tid >> 6, lane = tid & 63;
    const int ln = lane & 15, quad = lane >> 4;
    const size_t m0 = (size_t)blockIdx.y * 128;
    const int n0 = blockIdx.x * 128;
    const int wm = (wave >> 1) * 64, wn = (wave & 1) * 64;

    const floatx4 z4 = {0.f, 0.f, 0.f, 0.f};
    floatx4 acc[4][4];
    #pragma unroll
    for (int mt = 0; mt < 4; mt++)
        #pragma unroll
        for (int nt = 0; nt < 4; nt++) acc[mt][nt] = z4;

    // staging: 16 segs of 16 rows (1 KB each); wave w does A segs {w,w+4}, B segs {w,w+4}
    const int arow = wave * 16 + (lane >> 2);
    const int acol = (lane & 3) * 8;
    const unsigned short* gA = A + (m0 + (size_t)arow) * K + acol;
    const unsigned short* gB = W + ((size_t)(n0 + arow)) * K + acol;
    const size_t rs64 = (size_t)64 * K;
    unsigned short* lA0 = &sA[wave * 512];
    unsigned short* lA1 = &sA[(wave + 4) * 512];
    unsigned short* lB0 = &sB[wave * 512];
    unsigned short* lB1 = &sB[(wave + 4) * 512];

    for (int k0 = 0; k0 < K; k0 += 32) {
        load16(lA0, gA + k0);
        load16(lA1, gA + rs64 + k0);
        load16(lB0, gB + k0);
        load16(lB1, gB + rs64 + k0);
        __syncthreads();
        bf16x8 af[4], bfr[4];
        #pragma unroll
        for (int mt = 0; mt < 4; mt++)
            af[mt] = *(const bf16x8*)&sA[(wm + mt * 16 + ln) * 32 + quad * 8];
        #pragma unroll
        for (int nt = 0; nt < 4; nt++)
            bfr[nt] = *(const bf16x8*)&sB[(wn + nt * 16 + ln) * 32 + quad * 8];
        #pragma unroll
        for (int mt = 0; mt < 4; mt++)
            #pragma unroll
            for (int nt = 0; nt < 4; nt++)
                acc[mt][nt] = __builtin_amdgcn_mfma_f32_16x16x32_bf16(af[mt], bfr[nt], acc[mt][nt], 0, 0, 0);
        __syncthreads();
    }

    // epilogue: C/D layout col=lane&15, row=(lane>>4)*4+reg  [verified m89/m91]
    const size_t rowb = m0 + wm + quad * 4;
    const int colb = n0 + wn + ln;
    #pragma unroll
    for (int mt = 0; mt < 4; mt++) {
        #pragma unroll
        for (int nt = 0; nt < 4; nt++) {
            const int n = colb + nt * 16;
            const float bs = bias[n];
            #pragma unroll
            for (int r = 0; r < 4; r++) {
                const size_t row = rowb + mt * 16 + r;
                float c = acc[mt][nt][r] + bs;
                if constexpr (EPI == 0) {
                    int sect = n >> 10, d1 = n & 1023, h = d1 >> 6, d = d1 & 63;
                    int bb = (int)(row >> 11), s = (int)(row & 2047);
                    size_t bh = (size_t)(bb * 16 + h);
                    if (sect == 0)      ob0[(bh * 2048 + s) * 64 + d] = f2b(c);
                    else if (sect == 1) ob1[(bh * 2048 + s) * 64 + d] = f2b(c);
                    else                ob2[(bh * 64 + d) * 2048 + s] = f2b(c);  // V^T
                } else if constexpr (EPI == 1) {
                    size_t idx = row * 1024 + n;
                    ob0[idx] = f2b(c);                 // ctx (pre-residual) for INL
                    of0[idx] = xres[idx] + c;          // x1 = x + attn_out
                } else if constexpr (EPI == 2) {
                    int p = n >> 10;
                    float v;
                    if (p == 0)       v = c;                                            // u
                    else if (p == 2)  v = fmaxf(c, 0.f) + log1pf(__expf(-fabsf(c)));    // softplus
                    else              v = 1.f / (1.f + __expf(-c));                     // sigmoid
                    ob0[row * 4096 + n] = f2b(v);
                } else if constexpr (EPI == 3) {
                    float v = 0.5f * c * (1.f + erff(c * 0.70710678118654752f));        // exact GELU
                    ob0[row * 4096 + n] = f2b(v);
                } else {
                    size_t idx = row * 1024 + n;
                    of0[idx] += c;                     // final residual accumulate
                }
            }
        }
    }
}

// ---------------------------------------------------------------------------
// Flash causal attention. Q-tile 128 rows (block), K-tile 64 cols.
// 4 waves; wave owns 32 q-rows -> softmax state entirely wave-local.
// LDS: Q 16K + K 8K + Vt 8K + P 16K = 48 KB.
// ---------------------------------------------------------------------------
__global__ __launch_bounds__(256) void attn_kernel(const unsigned short* __restrict__ Qb,
                                                   const unsigned short* __restrict__ Kb,
                                                   const unsigned short* __restrict__ Vtb,
                                                   unsigned short* __restrict__ Ob) {
    __shared__ unsigned short sQ[128 * 64];
    __shared__ unsigned short sK[64 * 64];
    __shared__ unsigned short sVt[64 * 64];
    __shared__ unsigned short sP[4 * 32 * 64];
    const int qt = blockIdx.x, bh = blockIdx.y;
    const int tid = threadIdx.x, wave = tid >> 6, lane = tid & 63;
    const int ln = lane & 15, quad = lane >> 4;
    const int q0 = qt * 128;
    const unsigned short* Q  = Qb  + (size_t)bh * 2048 * 64;
    const unsigned short* Kp = Kb  + (size_t)bh * 2048 * 64;
    const unsigned short* Vt = Vtb + (size_t)bh * 64 * 2048;

    // stage Q once: 16 segs of 8 rows
    #pragma unroll
    for (int i = 0; i < 4; i++) {
        int s = wave * 4 + i;
        load16(&sQ[s * 512], Q + (size_t)(q0 + s * 8 + (lane >> 3)) * 64 + (lane & 7) * 8);
    }

    const floatx4 z4 = {0.f, 0.f, 0.f, 0.f};
    floatx4 Oacc[2][4];
    float m_run[2][4], l_run[2][4];
    #pragma unroll
    for (int mt = 0; mt < 2; mt++)
        #pragma unroll
        for (int j = 0; j < 4; j++) { Oacc[mt][j] = z4; m_run[mt][j] = -1e30f; l_run[mt][j] = 0.f; }

    for (int kk0 = 0; kk0 <= q0 + 64; kk0 += 64) {
        {   // stage K [64,64] and Vt [64,64]: 8 segs each, 2 per wave
            int s = wave * 2;
            const unsigned short* kg = Kp + (size_t)(kk0 + s * 8 + (lane >> 3)) * 64 + (lane & 7) * 8;
            load16(&sK[s * 512], kg);
            load16(&sK[(s + 1) * 512], kg + (size_t)8 * 64);
            const unsigned short* vg = Vt + (size_t)(s * 8 + (lane >> 3)) * 2048 + kk0 + (lane & 7) * 8;
            load16(&sVt[s * 512], vg);
            load16(&sVt[(s + 1) * 512], vg + (size_t)8 * 2048);
        }
        __syncthreads();

        // S = Q K^T
        floatx4 Sc[2][4];
        #pragma unroll
        for (int mt = 0; mt < 2; mt++)
            #pragma unroll
            for (int nt = 0; nt < 4; nt++) Sc[mt][nt] = z4;
        #pragma unroll
        for (int ks = 0; ks < 2; ks++) {
            bf16x8 aq[2];
            #pragma unroll
            for (int mt = 0; mt < 2; mt++)
                aq[mt] = *(const bf16x8*)&sQ[(wave * 32 + mt * 16 + ln) * 64 + ks * 32 + quad * 8];
            #pragma unroll
            for (int nt = 0; nt < 4; nt++) {
                bf16x8 bk = *(const bf16x8*)&sK[(nt * 16 + ln) * 64 + ks * 32 + quad * 8];
                #pragma unroll
                for (int mt = 0; mt < 2; mt++)
                    Sc[mt][nt] = __builtin_amdgcn_mfma_f32_16x16x32_bf16(aq[mt], bk, Sc[mt][nt], 0, 0, 0);
            }
        }

        const bool diag = (kk0 >= q0);
        #pragma unroll
        for (int mt = 0; mt < 2; mt++)
            #pragma unroll
            for (int nt = 0; nt < 4; nt++)
                #pragma unroll
                for (int r = 0; r < 4; r++) {
                    float v = Sc[mt][nt][r] * 0.125f;
                    if (diag) {
                        int rowg = q0 + wave * 32 + mt * 16 + quad * 4 + r;
                        int colg = kk0 + nt * 16 + ln;
                        if (colg > rowg) v = -1e30f;
                    }
                    Sc[mt][nt][r] = v;
                }

        // online softmax (rows live in one 16-lane quad)
        float alpha[2][4];
        #pragma unroll
        for (int mt = 0; mt < 2; mt++)
            #pragma unroll
            for (int r = 0; r < 4; r++) {
                float mx = fmaxf(fmaxf(Sc[mt][0][r], Sc[mt][1][r]), fmaxf(Sc[mt][2][r], Sc[mt][3][r]));
                #pragma unroll
                for (int off = 1; off < 16; off <<= 1) mx = fmaxf(mx, __shfl_xor(mx, off));
                float mnew = fmaxf(m_run[mt][r], mx);
                alpha[mt][r] = __expf(m_run[mt][r] - mnew);
                m_run[mt][r] = mnew;
            }
        #pragma unroll
        for (int mt = 0; mt < 2; mt++)
            #pragma unroll
            for (int r = 0; r < 4; r++) {
                float rs = 0.f;
                #pragma unroll
                for (int nt = 0; nt < 4; nt++) {
                    float p = __expf(Sc[mt][nt][r] - m_run[mt][r]);
                    Sc[mt][nt][r] = p;
                    rs += p;
                }
                #pragma unroll
                for (int off = 1; off < 16; off <<= 1) rs += __shfl_xor(rs, off);
                l_run[mt][r] = l_run[mt][r] * alpha[mt][r] + rs;
            }
        #pragma unroll
        for (int mt = 0; mt < 2; mt++)
            #pragma unroll
            for (int nt = 0; nt < 4; nt++)
                #pragma unroll
                for (int r = 0; r < 4; r++) Oacc[mt][nt][r] *= alpha[mt][r];

        // P -> LDS (C-layout scatter), wave-local region: no barrier needed
        #pragma unroll
        for (int mt = 0; mt < 2; mt++)
            #pragma unroll
            for (int nt = 0; nt < 4; nt++)
                #pragma unroll
                for (int r = 0; r < 4; r++)
                    sP[wave * 2048 + (mt * 16 + quad * 4 + r) * 64 + nt * 16 + ln] = f2b(Sc[mt][nt][r]);

        // O += P V
        #pragma unroll
        for (int kp = 0; kp < 2; kp++) {
            bf16x8 ap[2];
            #pragma unroll
            for (int mt = 0; mt < 2; mt++)
                ap[mt] = *(const bf16x8*)&sP[wave * 2048 + (mt * 16 + ln) * 64 + kp * 32 + quad * 8];
            #pragma unroll
            for (int nt = 0; nt < 4; nt++) {
                bf16x8 bv = *(const bf16x8*)&sVt[(nt * 16 + ln) * 64 + kp * 32 + quad * 8];
                #pragma unroll
                for (int mt = 0; mt < 2; mt++)
                    Oacc[mt][nt] = __builtin_amdgcn_mfma_f32_16x16x32_bf16(ap[mt], bv, Oacc[mt][nt], 0, 0, 0);
            }
        }
        __syncthreads();
    }

    const int bb = bh >> 4, h = bh & 15;
    #pragma unroll
    for (int mt = 0; mt < 2; mt++)
        #pragma unroll
        for (int nt = 0; nt < 4; nt++)
            #pragma unroll
            for (int r = 0; r < 4; r++) {
                float o = Oacc[mt][nt][r] / l_run[mt][r];
                int srow = q0 + wave * 32 + mt * 16 + quad * 4 + r;
                size_t tok = (size_t)bb * 2048 + srow;
                Ob[tok * 1024 + h * 64 + nt * 16 + ln] = f2b(o);
            }
}

// ---------------------------------------------------------------------------
extern "C" void kernel_launch(void* const* d_in, const int* in_sizes, int n_in,
                              void* d_out, int out_size, void* d_ws, size_t ws_size,
                              hipStream_t stream) {
    const float* x          = (const float*)d_in[0];
    const float* ln_attn_w  = (const float*)d_in[1];
    const float* ln_attn_b  = (const float*)d_in[2];
    const float* attn_in_w  = (const float*)d_in[3];
    const float* attn_in_b  = (const float*)d_in[4];
    const float* attn_out_w = (const float*)d_in[5];
    const float* attn_out_b = (const float*)d_in[6];
    const float* ln1_w      = (const float*)d_in[7];
    const float* ln1_b      = (const float*)d_in[8];
    const float* ln2_w      = (const float*)d_in[9];
    const float* ln2_b      = (const float*)d_in[10];
    const float* inl_u_w    = (const float*)d_in[11];
    const float* inl_u_b    = (const float*)d_in[12];
    const float* inl_a_w    = (const float*)d_in[13];
    const float* inl_a_b    = (const float*)d_in[14];
    const float* inl_b_w    = (const float*)d_in[15];
    const float* inl_b_b    = (const float*)d_in[16];
    const float* inl_g_w    = (const float*)d_in[17];
    const float* inl_g_b    = (const float*)d_in[18];
    const float* ff1_w      = (const float*)d_in[19];
    const float* ff1_b      = (const float*)d_in[20];
    const float* ff2_w      = (const float*)d_in[21];
    const float* ff2_b      = (const float*)d_in[22];
    float* out = (float*)d_out;

    char* ws = (char*)d_ws;
    unsigned short* Wqkv  = (unsigned short*)(ws);
    unsigned short* Wout  = (unsigned short*)(ws + 6291456);
    unsigned short* Winl  = (unsigned short*)(ws + 8388608);
    unsigned short* Wff1  = (unsigned short*)(ws + 16777216);
    unsigned short* Wff2  = (unsigned short*)(ws + 25165824);
    unsigned short* xnb   = (unsigned short*)(ws + 33554432);   // 16MB: xn, later h
    unsigned short* qb    = (unsigned short*)(ws + 50331648);   // 16MB
    unsigned short* kb    = (unsigned short*)(ws + 67108864);   // 16MB
    unsigned short* vtb   = (unsigned short*)(ws + 83886080);   // 16MB
    unsigned short* attnb = (unsigned short*)(ws + 100663296);  // 16MB
    unsigned short* ctxb  = (unsigned short*)(ws + 117440512);  // 16MB
    float*          xs    = (float*)(ws + 134217728);           // 32MB
    float*          bias4 = (float*)(ws + 167772160);           // 16KB
    unsigned short* uabg  = (unsigned short*)(ws + 50331648);   // 64MB, reuses q/k/vt/attn
    unsigned short* ff1b  = (unsigned short*)(ws + 50331648);   // 64MB, reuses uabg

    // 1. weight conversion (weights restored before every call)
    cvt_kernel<<<3072, 256, 0, stream>>>(attn_in_w, Wqkv, 786432);
    cvt_kernel<<<1024, 256, 0, stream>>>(attn_out_w, Wout, 262144);
    cvt_kernel<<<1024, 256, 0, stream>>>(inl_u_w, Winl + 0, 262144);
    cvt_kernel<<<1024, 256, 0, stream>>>(inl_a_w, Winl + 1048576, 262144);
    cvt_kernel<<<1024, 256, 0, stream>>>(inl_b_w, Winl + 2097152, 262144);
    cvt_kernel<<<1024, 256, 0, stream>>>(inl_g_w, Winl + 3145728, 262144);
    cvt_kernel<<<4096, 256, 0, stream>>>(ff1_w, Wff1, 1048576);
    cvt_kernel<<<4096, 256, 0, stream>>>(ff2_w, Wff2, 1048576);
    catbias_kernel<<<16, 256, 0, stream>>>(inl_u_b, inl_a_b, inl_b_b, inl_g_b, bias4);

    // 2. xn = LN(x)
    ln_kernel<<<8192, 256, 0, stream>>>(x, ln_attn_w, ln_attn_b, xnb, nullptr);
    // 3. qkv projection, scattered into per-head q/k/v^T
    gemm_bt<0><<<dim3(24, 64), 256, 0, stream>>>(xnb, Wqkv, attn_in_b, 1024, qb, kb, vtb, nullptr, nullptr);
    // 4. causal flash attention
    attn_kernel<<<dim3(16, 64), 256, 0, stream>>>(qb, kb, vtb, attnb);
    // 5. out-projection: ctx (bf16) + x1 = x + ctx -> d_out
    gemm_bt<1><<<dim3(8, 64), 256, 0, stream>>>(attnb, Wout, attn_out_b, 1024, ctxb, nullptr, nullptr, out, x);
    // 6. xs0 = LN(x1)
    ln_kernel<<<8192, 256, 0, stream>>>(out, ln1_w, ln1_b, nullptr, xs);
    // 7. fused INL controllers: u | sigmoid | softplus | sigmoid
    gemm_bt<2><<<dim3(32, 64), 256, 0, stream>>>(ctxb, Winl, bias4, 1024, uabg, nullptr, nullptr, nullptr, nullptr);
    // 8. integrator: x2 = x1 + xs(5 steps) -> d_out
    integrator_kernel<<<8192, 256, 0, stream>>>(xs, uabg, out);
    // 9. h = LN(x2)
    ln_kernel<<<8192, 256, 0, stream>>>(out, ln2_w, ln2_b, xnb, nullptr);
    // 10. FF1 + exact GELU
    gemm_bt<3><<<dim3(32, 64), 256, 0, stream>>>(xnb, Wff1, ff1_b, 1024, ff1b, nullptr, nullptr, nullptr, nullptr);
    // 11. FF2 + residual accumulate -> d_out
    gemm_bt<4><<<dim3(8, 64), 256, 0, stream>>>(ff1b, Wff2, ff2_b, 4096, nullptr, nullptr, nullptr, out, nullptr);
}

// Round 2
// 966.415 us; speedup vs baseline: 1.1034x; 1.1034x over previous
//
#include <hip/hip_runtime.h>
#include <cstdint>
#include <cmath>

typedef __attribute__((ext_vector_type(4))) float floatx4;
typedef __attribute__((ext_vector_type(8))) __bf16 bf16x8;
typedef __attribute__((ext_vector_type(4))) unsigned short ushort4v;

#define DEVI static __device__ __forceinline__

DEVI unsigned short f2b(float f) {
    unsigned x = __float_as_uint(f);
    return (unsigned short)((x + 0x7fffu + ((x >> 16) & 1u)) >> 16);
}
DEVI float b2f(unsigned short u) { return __uint_as_float(((unsigned)u) << 16); }

// async global->LDS, 16B per lane; LDS dest is wave-uniform base + lane*16
DEVI void load16(void* lds, const void* g) {
    __builtin_amdgcn_global_load_lds(
        (__attribute__((address_space(1))) void*)(const_cast<void*>(g)),
        (__attribute__((address_space(3))) void*)lds, 16, 0, 0);
}

// ---------------------------------------------------------------------------
// fp32 -> bf16 convert (vector x4)
// ---------------------------------------------------------------------------
__global__ __launch_bounds__(256) void cvt_kernel(const float* __restrict__ src,
                                                  unsigned short* __restrict__ dst, int n4) {
    int i = blockIdx.x * 256 + threadIdx.x;
    if (i >= n4) return;
    floatx4 v = ((const floatx4*)src)[i];
    ushort4v o;
    o[0] = f2b(v[0]); o[1] = f2b(v[1]); o[2] = f2b(v[2]); o[3] = f2b(v[3]);
    ((ushort4v*)dst)[i] = o;
}

__global__ __launch_bounds__(256) void catbias_kernel(const float* __restrict__ a,
                                                      const float* __restrict__ b,
                                                      const float* __restrict__ c,
                                                      const float* __restrict__ d,
                                                      float* __restrict__ o) {
    int i = blockIdx.x * 256 + threadIdx.x;   // 4096 total
    int p = i >> 10, j = i & 1023;
    float v = (p == 0) ? a[j] : (p == 1) ? b[j] : (p == 2) ? c[j] : d[j];
    o[i] = v;
}

// ---------------------------------------------------------------------------
// LayerNorm over D=1024: one block per row, optional bf16 and fp32 outputs
// ---------------------------------------------------------------------------
__global__ __launch_bounds__(256) void ln_kernel(const float* __restrict__ in,
                                                 const float* __restrict__ w,
                                                 const float* __restrict__ b,
                                                 unsigned short* __restrict__ obf,
                                                 float* __restrict__ of) {
    const int row = blockIdx.x, tid = threadIdx.x;
    const floatx4* pr = (const floatx4*)(in + (size_t)row * 1024);
    floatx4 v = pr[tid];
    float s  = v[0] + v[1] + v[2] + v[3];
    float ss = v[0]*v[0] + v[1]*v[1] + v[2]*v[2] + v[3]*v[3];
    #pragma unroll
    for (int o = 32; o >= 1; o >>= 1) { s += __shfl_xor(s, o); ss += __shfl_xor(ss, o); }
    __shared__ float red[8];
    int wv = tid >> 6, lane = tid & 63;
    if (lane == 0) { red[wv] = s; red[4 + wv] = ss; }
    __syncthreads();
    s  = red[0] + red[1] + red[2] + red[3];
    ss = red[4] + red[5] + red[6] + red[7];
    float mu  = s * (1.0f / 1024.0f);
    float var = ss * (1.0f / 1024.0f) - mu * mu;
    float rstd = rsqrtf(var + 1e-5f);
    floatx4 wv4 = ((const floatx4*)w)[tid];
    floatx4 bv4 = ((const floatx4*)b)[tid];
    floatx4 o;
    #pragma unroll
    for (int c = 0; c < 4; c++) o[c] = (v[c] - mu) * rstd * wv4[c] + bv4[c];
    if (obf) {
        ushort4v t;
        t[0] = f2b(o[0]); t[1] = f2b(o[1]); t[2] = f2b(o[2]); t[3] = f2b(o[3]);
        ((ushort4v*)(obf + (size_t)row * 1024))[tid] = t;
    }
    if (of) ((floatx4*)(of + (size_t)row * 1024))[tid] = o;
}

// ---------------------------------------------------------------------------
// INL integrator: 5 explicit steps in registers, then x2 = x1 + xs -> d_out
// ---------------------------------------------------------------------------
__global__ __launch_bounds__(256) void integrator_kernel(const float* __restrict__ xs0,
                                                         const unsigned short* __restrict__ uabg,
                                                         float* __restrict__ xio) {
    size_t i = (size_t)blockIdx.x * 256 + threadIdx.x;  // group of 4 elems
    size_t tok = i >> 8;
    int grp = (int)(i & 255) * 4;
    const unsigned short* ubase = uabg + tok * 4096 + grp;
    ushort4v uu = *(const ushort4v*)(ubase);
    ushort4v aa = *(const ushort4v*)(ubase + 1024);
    ushort4v bb = *(const ushort4v*)(ubase + 2048);
    ushort4v gg = *(const ushort4v*)(ubase + 3072);
    floatx4 xsv = ((const floatx4*)xs0)[i];
    floatx4 x1  = ((const floatx4*)xio)[i];
    floatx4 res;
    #pragma unroll
    for (int c = 0; c < 4; c++) {
        float u = b2f(uu[c]), a = b2f(aa[c]), bt = b2f(bb[c]), g = b2f(gg[c]);
        float xs = xsv[c], vs = 0.f;
        #pragma unroll
        for (int t = 0; t < 5; t++) {
            vs += 0.1f * (-a * xs - bt * vs + u);
            xs += 0.1f * g * vs;
        }
        res[c] = x1[c] + xs;
    }
    ((floatx4*)xio)[i] = res;
}

// ---------------------------------------------------------------------------
// bf16 GEMM: C[M,N] = A[M,K] @ W[N,K]^T (+bias) with fused epilogues.
// 128x128 tile, BK=32, 4 waves (2x2 of 64x64), 16x16x32 MFMA, m97 staging.
// EPI: 0=QKV scatter  1=out-proj(+residual,+ctx)  2=INL activations
//      3=FF1 GELU     4=FF2 accumulate into d_out
// ---------------------------------------------------------------------------
template <int EPI>
__global__ __launch_bounds__(256) void gemm_bt(const unsigned short* __restrict__ A,
                                               const unsigned short* __restrict__ W,
                                               const float* __restrict__ bias, int K,
                                               unsigned short* __restrict__ ob0,
                                               unsigned short* __restrict__ ob1,
                                               unsigned short* __restrict__ ob2,
                                               float* __restrict__ of0,
                                               const float* __restrict__ xres) {
    __shared__ unsigned short sA[128 * 32];
    __shared__ unsigned short sB[128 * 32];
    const int tid = threadIdx.x;
    const int wave = tid >> 6, lane = tid & 63;
    const int ln = lane & 15, quad = lane >> 4;
    const size_t m0 = (size_t)blockIdx.y * 128;
    const int n0 = blockIdx.x * 128;
    const int wm = (wave >> 1) * 64, wn = (wave & 1) * 64;

    const floatx4 z4 = {0.f, 0.f, 0.f, 0.f};
    floatx4 acc[4][4];
    #pragma unroll
    for (int mt = 0; mt < 4; mt++)
        #pragma unroll
        for (int nt = 0; nt < 4; nt++) acc[mt][nt] = z4;

    // staging: 16 segs of 16 rows (1 KB each); wave w does A segs {w,w+4}, B segs {w,w+4}
    const int arow = wave * 16 + (lane >> 2);
    const int acol = (lane & 3) * 8;
    const unsigned short* gA = A + (m0 + (size_t)arow) * K + acol;
    const unsigned short* gB = W + ((size_t)(n0 + arow)) * K + acol;
    const size_t rs64 = (size_t)64 * K;
    unsigned short* lA0 = &sA[wave * 512];
    unsigned short* lA1 = &sA[(wave + 4) * 512];
    unsigned short* lB0 = &sB[wave * 512];
    unsigned short* lB1 = &sB[(wave + 4) * 512];

    for (int k0 = 0; k0 < K; k0 += 32) {
        load16(lA0, gA + k0);
        load16(lA1, gA + rs64 + k0);
        load16(lB0, gB + k0);
        load16(lB1, gB + rs64 + k0);
        __syncthreads();
        bf16x8 af[4], bfr[4];
        #pragma unroll
        for (int mt = 0; mt < 4; mt++)
            af[mt] = *(const bf16x8*)&sA[(wm + mt * 16 + ln) * 32 + quad * 8];
        #pragma unroll
        for (int nt = 0; nt < 4; nt++)
            bfr[nt] = *(const bf16x8*)&sB[(wn + nt * 16 + ln) * 32 + quad * 8];
        #pragma unroll
        for (int mt = 0; mt < 4; mt++)
            #pragma unroll
            for (int nt = 0; nt < 4; nt++)
                acc[mt][nt] = __builtin_amdgcn_mfma_f32_16x16x32_bf16(af[mt], bfr[nt], acc[mt][nt], 0, 0, 0);
        __syncthreads();
    }

    // epilogue: C/D layout col=lane&15, row=(lane>>4)*4+reg  [verified m89/m91]
    const size_t rowb = m0 + wm + quad * 4;
    const int colb = n0 + wn + ln;
    #pragma unroll
    for (int mt = 0; mt < 4; mt++) {
        #pragma unroll
        for (int nt = 0; nt < 4; nt++) {
            const int n = colb + nt * 16;
            const float bs = bias[n];
            #pragma unroll
            for (int r = 0; r < 4; r++) {
                const size_t row = rowb + mt * 16 + r;
                float c = acc[mt][nt][r] + bs;
                if constexpr (EPI == 0) {
                    int sect = n >> 10, d1 = n & 1023, h = d1 >> 6, d = d1 & 63;
                    int bb = (int)(row >> 11), s = (int)(row & 2047);
                    size_t bh = (size_t)(bb * 16 + h);
                    if (sect == 0)      ob0[(bh * 2048 + s) * 64 + d] = f2b(c);
                    else if (sect == 1) ob1[(bh * 2048 + s) * 64 + d] = f2b(c);
                    else                ob2[(bh * 64 + d) * 2048 + s] = f2b(c);  // V^T
                } else if constexpr (EPI == 1) {
                    size_t idx = row * 1024 + n;
                    ob0[idx] = f2b(c);                 // ctx (pre-residual) for INL
                    of0[idx] = xres[idx] + c;          // x1 = x + attn_out
                } else if constexpr (EPI == 2) {
                    int p = n >> 10;
                    float v;
                    if (p == 0)       v = c;                                            // u
                    else if (p == 2)  v = fmaxf(c, 0.f) + log1pf(__expf(-fabsf(c)));    // softplus
                    else              v = 1.f / (1.f + __expf(-c));                     // sigmoid
                    ob0[row * 4096 + n] = f2b(v);
                } else if constexpr (EPI == 3) {
                    float v = 0.5f * c * (1.f + erff(c * 0.70710678118654752f));        // exact GELU
                    ob0[row * 4096 + n] = f2b(v);
                } else {
                    size_t idx = row * 1024 + n;
                    of0[idx] += c;                     // final residual accumulate
                }
            }
        }
    }
}

// ---------------------------------------------------------------------------
// Flash causal attention v2.
//  - Q-tile 128 rows/block, 4 waves, wave owns 32 q-rows (softmax wave-local)
//  - K-tile 64 cols, double-buffered K/Vt staging, ONE barrier per k-tile
//  - Q fragments held in registers; Q-staging LDS reused as P buffer
//  - XOR granule swizzle on K/Vt/Q staging -> conflict-free b128 reads
//  - P buffer stride 72 (16B-aligned rows, conflict-free store/read)
// LDS: sK 16K + sVt 16K + sQP 18K = 50 KB -> 3 blocks/CU
// ---------------------------------------------------------------------------
#define PSTR 72
__global__ __launch_bounds__(256, 3) void attn_kernel(const unsigned short* __restrict__ Qb,
                                                      const unsigned short* __restrict__ Kb,
                                                      const unsigned short* __restrict__ Vtb,
                                                      unsigned short* __restrict__ Ob) {
    __shared__ unsigned short sK[2][64 * 64];
    __shared__ unsigned short sVt[2][64 * 64];
    __shared__ unsigned short sQP[128 * PSTR];
    const int qt = (int)gridDim.x - 1 - (int)blockIdx.x;  // long blocks first
    const int bh = blockIdx.y;
    const int tid = threadIdx.x, wave = tid >> 6, lane = tid & 63;
    const int ln = lane & 15, quad = lane >> 4;
    const int q0 = qt * 128;
    const unsigned short* Q  = Qb  + (size_t)bh * 2048 * 64;
    const unsigned short* Kp = Kb  + (size_t)bh * 2048 * 64;
    const unsigned short* Vt = Vtb + (size_t)bh * 64 * 2048;

    const int rl  = lane >> 3;                    // row-in-seg 0..7
    const int gsw = (((lane & 7) ^ rl)) * 8;      // swizzled 16B-granule col (ushorts)

    // stage Q once (swizzled): 16 segs of 8 rows
    #pragma unroll
    for (int i = 0; i < 4; i++) {
        int s = wave * 4 + i;
        load16(&sQP[s * 512], Q + (size_t)(q0 + s * 8 + rl) * 64 + gsw);
    }
    // prefetch K/Vt tile 0 (swizzled)
    const int sseg = wave * 2;
    const unsigned short* kbase = Kp + (size_t)(sseg * 8 + rl) * 64 + gsw;
    const unsigned short* vbase = Vt + (size_t)(sseg * 8 + rl) * 2048 + gsw;
    load16(&sK[0][sseg * 512], kbase);
    load16(&sK[0][(sseg + 1) * 512], kbase + (size_t)8 * 64);
    load16(&sVt[0][sseg * 512], vbase);
    load16(&sVt[0][(sseg + 1) * 512], vbase + (size_t)8 * 2048);
    __syncthreads();

    // Q fragments -> registers (swizzled read), rows = wave*32 + mt*16 + ln
    bf16x8 aq[2][2];
    #pragma unroll
    for (int mt = 0; mt < 2; mt++)
        #pragma unroll
        for (int ks = 0; ks < 2; ks++)
            aq[mt][ks] = *(const bf16x8*)&sQP[(wave * 32 + mt * 16 + ln) * 64 +
                                              (((ks * 4 + quad) ^ (ln & 7)) * 8)];
    __syncthreads();  // all Q reads complete before sQP is reused as P

    unsigned short* sP = &sQP[wave * 32 * PSTR];  // per-wave P region

    const floatx4 z4 = {0.f, 0.f, 0.f, 0.f};
    floatx4 Oacc[2][4];
    float m_run[2][4], l_run[2][4];
    #pragma unroll
    for (int mt = 0; mt < 2; mt++)
        #pragma unroll
        for (int j = 0; j < 4; j++) { Oacc[mt][j] = z4; m_run[mt][j] = -1e30f; l_run[mt][j] = 0.f; }

    const int T = 2 * qt + 2;
    const int wave_first = q0 + wave * 32;
    const int wave_last  = wave_first + 31;

    for (int t = 0; t < T; t++) {
        const int kk0 = t * 64;
        const int cur = t & 1;
        if (t + 1 < T) {  // prefetch next tile into other buffer
            const unsigned short* kg = kbase + (size_t)(kk0 + 64) * 64;
            const unsigned short* vg = vbase + (size_t)(kk0 + 64);
            load16(&sK[cur ^ 1][sseg * 512], kg);
            load16(&sK[cur ^ 1][(sseg + 1) * 512], kg + (size_t)8 * 64);
            load16(&sVt[cur ^ 1][sseg * 512], vg);
            load16(&sVt[cur ^ 1][(sseg + 1) * 512], vg + (size_t)8 * 2048);
        }
        if (kk0 <= wave_last) {  // wave-uniform: skip fully-masked tiles
            // S = Q K^T
            floatx4 Sc[2][4];
            #pragma unroll
            for (int mt = 0; mt < 2; mt++)
                #pragma unroll
                for (int nt = 0; nt < 4; nt++) Sc[mt][nt] = z4;
            #pragma unroll
            for (int ks = 0; ks < 2; ks++) {
                #pragma unroll
                for (int nt = 0; nt < 4; nt++) {
                    bf16x8 bk = *(const bf16x8*)&sK[cur][(nt * 16 + ln) * 64 +
                                                         (((ks * 4 + quad) ^ (ln & 7)) * 8)];
                    #pragma unroll
                    for (int mt = 0; mt < 2; mt++)
                        Sc[mt][nt] = __builtin_amdgcn_mfma_f32_16x16x32_bf16(aq[mt][ks], bk, Sc[mt][nt], 0, 0, 0);
                }
            }
            // scale + causal mask
            const bool diag = (kk0 + 63 > wave_first);
            #pragma unroll
            for (int mt = 0; mt < 2; mt++)
                #pragma unroll
                for (int nt = 0; nt < 4; nt++)
                    #pragma unroll
                    for (int r = 0; r < 4; r++) {
                        float v = Sc[mt][nt][r] * 0.125f;
                        if (diag) {
                            int rowg = wave_first + mt * 16 + quad * 4 + r;
                            int colg = kk0 + nt * 16 + ln;
                            if (colg > rowg) v = -1e30f;
                        }
                        Sc[mt][nt][r] = v;
                    }
            // online softmax (row spread across 16 lanes of a quad)
            float alpha[2][4];
            #pragma unroll
            for (int mt = 0; mt < 2; mt++)
                #pragma unroll
                for (int r = 0; r < 4; r++) {
                    float mx = fmaxf(fmaxf(Sc[mt][0][r], Sc[mt][1][r]), fmaxf(Sc[mt][2][r], Sc[mt][3][r]));
                    #pragma unroll
                    for (int off = 1; off < 16; off <<= 1) mx = fmaxf(mx, __shfl_xor(mx, off));
                    float mnew = fmaxf(m_run[mt][r], mx);
                    alpha[mt][r] = __expf(m_run[mt][r] - mnew);
                    m_run[mt][r] = mnew;
                }
            #pragma unroll
            for (int mt = 0; mt < 2; mt++)
                #pragma unroll
                for (int r = 0; r < 4; r++) {
                    float rs = 0.f;
                    #pragma unroll
                    for (int nt = 0; nt < 4; nt++) {
                        float p = __expf(Sc[mt][nt][r] - m_run[mt][r]);
                        Sc[mt][nt][r] = p;
                        rs += p;
                    }
                    #pragma unroll
                    for (int off = 1; off < 16; off <<= 1) rs += __shfl_xor(rs, off);
                    l_run[mt][r] = l_run[mt][r] * alpha[mt][r] + rs;
                }
            #pragma unroll
            for (int mt = 0; mt < 2; mt++)
                #pragma unroll
                for (int nt = 0; nt < 4; nt++)
                    #pragma unroll
                    for (int r = 0; r < 4; r++) Oacc[mt][nt][r] *= alpha[mt][r];
            // P -> per-wave LDS region (stride 72: conflict-free)
            #pragma unroll
            for (int mt = 0; mt < 2; mt++)
                #pragma unroll
                for (int nt = 0; nt < 4; nt++)
                    #pragma unroll
                    for (int r = 0; r < 4; r++)
                        sP[(mt * 16 + quad * 4 + r) * PSTR + nt * 16 + ln] = f2b(Sc[mt][nt][r]);
            // O += P V
            #pragma unroll
            for (int kp = 0; kp < 2; kp++) {
                bf16x8 ap[2];
                #pragma unroll
                for (int mt = 0; mt < 2; mt++)
                    ap[mt] = *(const bf16x8*)&sP[(mt * 16 + ln) * PSTR + kp * 32 + quad * 8];
                #pragma unroll
                for (int nt = 0; nt < 4; nt++) {
                    bf16x8 bv = *(const bf16x8*)&sVt[cur][(nt * 16 + ln) * 64 +
                                                          (((kp * 4 + quad) ^ (ln & 7)) * 8)];
                    #pragma unroll
                    for (int mt = 0; mt < 2; mt++)
                        Oacc[mt][nt] = __builtin_amdgcn_mfma_f32_16x16x32_bf16(ap[mt], bv, Oacc[mt][nt], 0, 0, 0);
                }
            }
        }
        __syncthreads();
    }

    const int bb = bh >> 4, h = bh & 15;
    #pragma unroll
    for (int mt = 0; mt < 2; mt++)
        #pragma unroll
        for (int nt = 0; nt < 4; nt++)
            #pragma unroll
            for (int r = 0; r < 4; r++) {
                float o = Oacc[mt][nt][r] / l_run[mt][r];
                int srow = q0 + wave * 32 + mt * 16 + quad * 4 + r;
                size_t tok = (size_t)bb * 2048 + srow;
                Ob[tok * 1024 + h * 64 + nt * 16 + ln] = f2b(o);
            }
}

// ---------------------------------------------------------------------------
extern "C" void kernel_launch(void* const* d_in, const int* in_sizes, int n_in,
                              void* d_out, int out_size, void* d_ws, size_t ws_size,
                              hipStream_t stream) {
    const float* x          = (const float*)d_in[0];
    const float* ln_attn_w  = (const float*)d_in[1];
    const float* ln_attn_b  = (const float*)d_in[2];
    const float* attn_in_w  = (const float*)d_in[3];
    const float* attn_in_b  = (const float*)d_in[4];
    const float* attn_out_w = (const float*)d_in[5];
    const float* attn_out_b = (const float*)d_in[6];
    const float* ln1_w      = (const float*)d_in[7];
    const float* ln1_b      = (const float*)d_in[8];
    const float* ln2_w      = (const float*)d_in[9];
    const float* ln2_b      = (const float*)d_in[10];
    const float* inl_u_w    = (const float*)d_in[11];
    const float* inl_u_b    = (const float*)d_in[12];
    const float* inl_a_w    = (const float*)d_in[13];
    const float* inl_a_b    = (const float*)d_in[14];
    const float* inl_b_w    = (const float*)d_in[15];
    const float* inl_b_b    = (const float*)d_in[16];
    const float* inl_g_w    = (const float*)d_in[17];
    const float* inl_g_b    = (const float*)d_in[18];
    const float* ff1_w      = (const float*)d_in[19];
    const float* ff1_b      = (const float*)d_in[20];
    const float* ff2_w      = (const float*)d_in[21];
    const float* ff2_b      = (const float*)d_in[22];
    float* out = (float*)d_out;

    char* ws = (char*)d_ws;
    unsigned short* Wqkv  = (unsigned short*)(ws);
    unsigned short* Wout  = (unsigned short*)(ws + 6291456);
    unsigned short* Winl  = (unsigned short*)(ws + 8388608);
    unsigned short* Wff1  = (unsigned short*)(ws + 16777216);
    unsigned short* Wff2  = (unsigned short*)(ws + 25165824);
    unsigned short* xnb   = (unsigned short*)(ws + 33554432);   // 16MB: xn, later h
    unsigned short* qb    = (unsigned short*)(ws + 50331648);   // 16MB
    unsigned short* kb    = (unsigned short*)(ws + 67108864);   // 16MB
    unsigned short* vtb   = (unsigned short*)(ws + 83886080);   // 16MB
    unsigned short* attnb = (unsigned short*)(ws + 100663296);  // 16MB
    unsigned short* ctxb  = (unsigned short*)(ws + 117440512);  // 16MB
    float*          xs    = (float*)(ws + 134217728);           // 32MB
    float*          bias4 = (float*)(ws + 167772160);           // 16KB
    unsigned short* uabg  = (unsigned short*)(ws + 50331648);   // 64MB, reuses q/k/vt/attn
    unsigned short* ff1b  = (unsigned short*)(ws + 50331648);   // 64MB, reuses uabg

    // 1. weight conversion (weights restored before every call)
    cvt_kernel<<<3072, 256, 0, stream>>>(attn_in_w, Wqkv, 786432);
    cvt_kernel<<<1024, 256, 0, stream>>>(attn_out_w, Wout, 262144);
    cvt_kernel<<<1024, 256, 0, stream>>>(inl_u_w, Winl + 0, 262144);
    cvt_kernel<<<1024, 256, 0, stream>>>(inl_a_w, Winl + 1048576, 262144);
    cvt_kernel<<<1024, 256, 0, stream>>>(inl_b_w, Winl + 2097152, 262144);
    cvt_kernel<<<1024, 256, 0, stream>>>(inl_g_w, Winl + 3145728, 262144);
    cvt_kernel<<<4096, 256, 0, stream>>>(ff1_w, Wff1, 1048576);
    cvt_kernel<<<4096, 256, 0, stream>>>(ff2_w, Wff2, 1048576);
    catbias_kernel<<<16, 256, 0, stream>>>(inl_u_b, inl_a_b, inl_b_b, inl_g_b, bias4);

    // 2. xn = LN(x)
    ln_kernel<<<8192, 256, 0, stream>>>(x, ln_attn_w, ln_attn_b, xnb, nullptr);
    // 3. qkv projection, scattered into per-head q/k/v^T
    gemm_bt<0><<<dim3(24, 64), 256, 0, stream>>>(xnb, Wqkv, attn_in_b, 1024, qb, kb, vtb, nullptr, nullptr);
    // 4. causal flash attention
    attn_kernel<<<dim3(16, 64), 256, 0, stream>>>(qb, kb, vtb, attnb);
    // 5. out-projection: ctx (bf16) + x1 = x + ctx -> d_out
    gemm_bt<1><<<dim3(8, 64), 256, 0, stream>>>(attnb, Wout, attn_out_b, 1024, ctxb, nullptr, nullptr, out, x);
    // 6. xs0 = LN(x1)
    ln_kernel<<<8192, 256, 0, stream>>>(out, ln1_w, ln1_b, nullptr, xs);
    // 7. fused INL controllers: u | sigmoid | softplus | sigmoid
    gemm_bt<2><<<dim3(32, 64), 256, 0, stream>>>(ctxb, Winl, bias4, 1024, uabg, nullptr, nullptr, nullptr, nullptr);
    // 8. integrator: x2 = x1 + xs(5 steps) -> d_out
    integrator_kernel<<<8192, 256, 0, stream>>>(xs, uabg, out);
    // 9. h = LN(x2)
    ln_kernel<<<8192, 256, 0, stream>>>(out, ln2_w, ln2_b, xnb, nullptr);
    // 10. FF1 + exact GELU
    gemm_bt<3><<<dim3(32, 64), 256, 0, stream>>>(xnb, Wff1, ff1_b, 1024, ff1b, nullptr, nullptr, nullptr, nullptr);
    // 11. FF2 + residual accumulate -> d_out
    gemm_bt<4><<<dim3(8, 64), 256, 0, stream>>>(ff1b, Wff2, ff2_b, 4096, nullptr, nullptr, nullptr, out, nullptr);
}

// Round 3
// 915.348 us; speedup vs baseline: 1.1649x; 1.0558x over previous
//
#include <hip/hip_runtime.h>
#include <cstdint>
#include <cmath>

typedef __attribute__((ext_vector_type(4))) float floatx4;
typedef __attribute__((ext_vector_type(8))) __bf16 bf16x8;
typedef __attribute__((ext_vector_type(4))) unsigned short ushort4v;

#define DEVI static __device__ __forceinline__

DEVI unsigned short f2b(float f) {
    unsigned x = __float_as_uint(f);
    return (unsigned short)((x + 0x7fffu + ((x >> 16) & 1u)) >> 16);
}
DEVI float b2f(unsigned short u) { return __uint_as_float(((unsigned)u) << 16); }

// async global->LDS, 16B per lane; LDS dest is wave-uniform base + lane*16
DEVI void load16(void* lds, const void* g) {
    __builtin_amdgcn_global_load_lds(
        (__attribute__((address_space(1))) void*)(const_cast<void*>(g)),
        (__attribute__((address_space(3))) void*)lds, 16, 0, 0);
}

// ---------------------------------------------------------------------------
// fp32 -> bf16 convert (vector x4)
// ---------------------------------------------------------------------------
__global__ __launch_bounds__(256) void cvt_kernel(const float* __restrict__ src,
                                                  unsigned short* __restrict__ dst, int n4) {
    int i = blockIdx.x * 256 + threadIdx.x;
    if (i >= n4) return;
    floatx4 v = ((const floatx4*)src)[i];
    ushort4v o;
    o[0] = f2b(v[0]); o[1] = f2b(v[1]); o[2] = f2b(v[2]); o[3] = f2b(v[3]);
    ((ushort4v*)dst)[i] = o;
}

__global__ __launch_bounds__(256) void catbias_kernel(const float* __restrict__ a,
                                                      const float* __restrict__ b,
                                                      const float* __restrict__ c,
                                                      const float* __restrict__ d,
                                                      float* __restrict__ o) {
    int i = blockIdx.x * 256 + threadIdx.x;   // 4096 total
    int p = i >> 10, j = i & 1023;
    float v = (p == 0) ? a[j] : (p == 1) ? b[j] : (p == 2) ? c[j] : d[j];
    o[i] = v;
}

// ---------------------------------------------------------------------------
// LayerNorm over D=1024: one block per row, optional bf16 and fp32 outputs
// ---------------------------------------------------------------------------
__global__ __launch_bounds__(256) void ln_kernel(const float* __restrict__ in,
                                                 const float* __restrict__ w,
                                                 const float* __restrict__ b,
                                                 unsigned short* __restrict__ obf,
                                                 float* __restrict__ of) {
    const int row = blockIdx.x, tid = threadIdx.x;
    const floatx4* pr = (const floatx4*)(in + (size_t)row * 1024);
    floatx4 v = pr[tid];
    float s  = v[0] + v[1] + v[2] + v[3];
    float ss = v[0]*v[0] + v[1]*v[1] + v[2]*v[2] + v[3]*v[3];
    #pragma unroll
    for (int o = 32; o >= 1; o >>= 1) { s += __shfl_xor(s, o); ss += __shfl_xor(ss, o); }
    __shared__ float red[8];
    int wv = tid >> 6, lane = tid & 63;
    if (lane == 0) { red[wv] = s; red[4 + wv] = ss; }
    __syncthreads();
    s  = red[0] + red[1] + red[2] + red[3];
    ss = red[4] + red[5] + red[6] + red[7];
    float mu  = s * (1.0f / 1024.0f);
    float var = ss * (1.0f / 1024.0f) - mu * mu;
    float rstd = rsqrtf(var + 1e-5f);
    floatx4 wv4 = ((const floatx4*)w)[tid];
    floatx4 bv4 = ((const floatx4*)b)[tid];
    floatx4 o;
    #pragma unroll
    for (int c = 0; c < 4; c++) o[c] = (v[c] - mu) * rstd * wv4[c] + bv4[c];
    if (obf) {
        ushort4v t;
        t[0] = f2b(o[0]); t[1] = f2b(o[1]); t[2] = f2b(o[2]); t[3] = f2b(o[3]);
        ((ushort4v*)(obf + (size_t)row * 1024))[tid] = t;
    }
    if (of) ((floatx4*)(of + (size_t)row * 1024))[tid] = o;
}

// ---------------------------------------------------------------------------
// INL integrator: 5 explicit steps in registers, then x2 = x1 + xs -> d_out
// ---------------------------------------------------------------------------
__global__ __launch_bounds__(256) void integrator_kernel(const float* __restrict__ xs0,
                                                         const unsigned short* __restrict__ uabg,
                                                         float* __restrict__ xio) {
    size_t i = (size_t)blockIdx.x * 256 + threadIdx.x;  // group of 4 elems
    size_t tok = i >> 8;
    int grp = (int)(i & 255) * 4;
    const unsigned short* ubase = uabg + tok * 4096 + grp;
    ushort4v uu = *(const ushort4v*)(ubase);
    ushort4v aa = *(const ushort4v*)(ubase + 1024);
    ushort4v bb = *(const ushort4v*)(ubase + 2048);
    ushort4v gg = *(const ushort4v*)(ubase + 3072);
    floatx4 xsv = ((const floatx4*)xs0)[i];
    floatx4 x1  = ((const floatx4*)xio)[i];
    floatx4 res;
    #pragma unroll
    for (int c = 0; c < 4; c++) {
        float u = b2f(uu[c]), a = b2f(aa[c]), bt = b2f(bb[c]), g = b2f(gg[c]);
        float xs = xsv[c], vs = 0.f;
        #pragma unroll
        for (int t = 0; t < 5; t++) {
            vs += 0.1f * (-a * xs - bt * vs + u);
            xs += 0.1f * g * vs;
        }
        res[c] = x1[c] + xs;
    }
    ((floatx4*)xio)[i] = res;
}

// ---------------------------------------------------------------------------
// bf16 GEMM: C[M,N] = A[M,K] @ W[N,K]^T (+bias) with fused epilogues.
// 128x128 tile, BK=32, 4 waves (2x2 of 64x64), 16x16x32 MFMA, m97 staging.
// EPI: 0=QKV scatter  1=out-proj(+residual,+ctx)  2=INL activations
//      3=FF1 GELU     4=FF2 accumulate into d_out
// ---------------------------------------------------------------------------
template <int EPI>
__global__ __launch_bounds__(256) void gemm_bt(const unsigned short* __restrict__ A,
                                               const unsigned short* __restrict__ W,
                                               const float* __restrict__ bias, int K,
                                               unsigned short* __restrict__ ob0,
                                               unsigned short* __restrict__ ob1,
                                               unsigned short* __restrict__ ob2,
                                               float* __restrict__ of0,
                                               const float* __restrict__ xres) {
    __shared__ unsigned short sA[128 * 32];
    __shared__ unsigned short sB[128 * 32];
    const int tid = threadIdx.x;
    const int wave = tid >> 6, lane = tid & 63;
    const int ln = lane & 15, quad = lane >> 4;
    const size_t m0 = (size_t)blockIdx.y * 128;
    const int n0 = blockIdx.x * 128;
    const int wm = (wave >> 1) * 64, wn = (wave & 1) * 64;

    const floatx4 z4 = {0.f, 0.f, 0.f, 0.f};
    floatx4 acc[4][4];
    #pragma unroll
    for (int mt = 0; mt < 4; mt++)
        #pragma unroll
        for (int nt = 0; nt < 4; nt++) acc[mt][nt] = z4;

    // staging: 16 segs of 16 rows (1 KB each); wave w does A segs {w,w+4}, B segs {w,w+4}
    const int arow = wave * 16 + (lane >> 2);
    const int acol = (lane & 3) * 8;
    const unsigned short* gA = A + (m0 + (size_t)arow) * K + acol;
    const unsigned short* gB = W + ((size_t)(n0 + arow)) * K + acol;
    const size_t rs64 = (size_t)64 * K;
    unsigned short* lA0 = &sA[wave * 512];
    unsigned short* lA1 = &sA[(wave + 4) * 512];
    unsigned short* lB0 = &sB[wave * 512];
    unsigned short* lB1 = &sB[(wave + 4) * 512];

    for (int k0 = 0; k0 < K; k0 += 32) {
        load16(lA0, gA + k0);
        load16(lA1, gA + rs64 + k0);
        load16(lB0, gB + k0);
        load16(lB1, gB + rs64 + k0);
        __syncthreads();
        bf16x8 af[4], bfr[4];
        #pragma unroll
        for (int mt = 0; mt < 4; mt++)
            af[mt] = *(const bf16x8*)&sA[(wm + mt * 16 + ln) * 32 + quad * 8];
        #pragma unroll
        for (int nt = 0; nt < 4; nt++)
            bfr[nt] = *(const bf16x8*)&sB[(wn + nt * 16 + ln) * 32 + quad * 8];
        #pragma unroll
        for (int mt = 0; mt < 4; mt++)
            #pragma unroll
            for (int nt = 0; nt < 4; nt++)
                acc[mt][nt] = __builtin_amdgcn_mfma_f32_16x16x32_bf16(af[mt], bfr[nt], acc[mt][nt], 0, 0, 0);
        __syncthreads();
    }

    // epilogue: C/D layout col=lane&15, row=(lane>>4)*4+reg  [verified m89/m91]
    const size_t rowb = m0 + wm + quad * 4;
    const int colb = n0 + wn + ln;
    #pragma unroll
    for (int mt = 0; mt < 4; mt++) {
        #pragma unroll
        for (int nt = 0; nt < 4; nt++) {
            const int n = colb + nt * 16;
            const float bs = bias[n];
            #pragma unroll
            for (int r = 0; r < 4; r++) {
                const size_t row = rowb + mt * 16 + r;
                float c = acc[mt][nt][r] + bs;
                if constexpr (EPI == 0) {
                    int sect = n >> 10, d1 = n & 1023, h = d1 >> 6, d = d1 & 63;
                    int bb = (int)(row >> 11), s = (int)(row & 2047);
                    size_t bh = (size_t)(bb * 16 + h);
                    if (sect == 0)      ob0[(bh * 2048 + s) * 64 + d] = f2b(c);
                    else if (sect == 1) ob1[(bh * 2048 + s) * 64 + d] = f2b(c);
                    else                ob2[(bh * 64 + d) * 2048 + s] = f2b(c);  // V^T
                } else if constexpr (EPI == 1) {
                    size_t idx = row * 1024 + n;
                    ob0[idx] = f2b(c);                 // ctx (pre-residual) for INL
                    of0[idx] = xres[idx] + c;          // x1 = x + attn_out
                } else if constexpr (EPI == 2) {
                    int p = n >> 10;
                    float v;
                    if (p == 0)       v = c;                                            // u
                    else if (p == 2)  v = fmaxf(c, 0.f) + log1pf(__expf(-fabsf(c)));    // softplus
                    else              v = 1.f / (1.f + __expf(-c));                     // sigmoid
                    ob0[row * 4096 + n] = f2b(v);
                } else if constexpr (EPI == 3) {
                    float v = 0.5f * c * (1.f + erff(c * 0.70710678118654752f));        // exact GELU
                    ob0[row * 4096 + n] = f2b(v);
                } else {
                    size_t idx = row * 1024 + n;
                    of0[idx] += c;                     // final residual accumulate
                }
            }
        }
    }
}

// ---------------------------------------------------------------------------
// Flash causal attention v3.
//  - balanced pairing: block pr handles Q-tiles {15-pr, pr} -> every block
//    does exactly 34 k-tile iterations; grid 8x64 = 512 uniform blocks
//  - raw-barrier pipeline: per k-tile, issue 4 prefetch global_load_lds then
//    s_waitcnt vmcnt(4) (waits PREVIOUS iteration's loads only -> full-
//    iteration prefetch distance, never vmcnt(0) in steady state) + s_barrier;
//    bare s_barrier after compute protects double-buffer overwrite
//  - Q fragments in registers; Q-staging LDS reused as P buffer (stride 72)
//  - XOR granule swizzle -> conflict-free b128 reads
// LDS: sK 16K + sVt 16K + sQP 18K = 50 KB
// ---------------------------------------------------------------------------
#define PSTR 72
__global__ __launch_bounds__(256, 3) void attn_kernel(const unsigned short* __restrict__ Qb,
                                                      const unsigned short* __restrict__ Kb,
                                                      const unsigned short* __restrict__ Vtb,
                                                      unsigned short* __restrict__ Ob) {
    __shared__ unsigned short sK[2][64 * 64];
    __shared__ unsigned short sVt[2][64 * 64];
    __shared__ unsigned short sQP[128 * PSTR];
    const int pr = blockIdx.x;   // pair index 0..7
    const int bh = blockIdx.y;
    const int tid = threadIdx.x, wave = tid >> 6, lane = tid & 63;
    const int ln = lane & 15, quad = lane >> 4;
    const unsigned short* Q  = Qb  + (size_t)bh * 2048 * 64;
    const unsigned short* Kp = Kb  + (size_t)bh * 2048 * 64;
    const unsigned short* Vt = Vtb + (size_t)bh * 64 * 2048;

    const int rl  = lane >> 3;                    // row-in-seg 0..7
    const int gsw = (((lane & 7) ^ rl)) * 8;      // swizzled 16B-granule col (ushorts)
    const int sseg = wave * 2;
    const unsigned short* kbase = Kp + (size_t)(sseg * 8 + rl) * 64 + gsw;
    const unsigned short* vbase = Vt + (size_t)(sseg * 8 + rl) * 2048 + gsw;
    unsigned short* sP = &sQP[wave * 32 * PSTR];  // per-wave P region
    const int bb = bh >> 4, h = bh & 15;
    const floatx4 z4 = {0.f, 0.f, 0.f, 0.f};

    #pragma unroll 1
    for (int phase = 0; phase < 2; phase++) {
        const int qt = phase ? pr : (15 - pr);    // long phase first
        const int q0 = qt * 128;
        const int T = 2 * qt + 2;

        // stage Q (swizzled, stride-64 into sQP) + prefetch K/V tile 0
        #pragma unroll
        for (int i = 0; i < 4; i++) {
            int s = wave * 4 + i;
            load16(&sQP[s * 512], Q + (size_t)(q0 + s * 8 + rl) * 64 + gsw);
        }
        load16(&sK[0][sseg * 512], kbase);
        load16(&sK[0][(sseg + 1) * 512], kbase + (size_t)8 * 64);
        load16(&sVt[0][sseg * 512], vbase);
        load16(&sVt[0][(sseg + 1) * 512], vbase + (size_t)8 * 2048);
        asm volatile("s_waitcnt vmcnt(0)" ::: "memory");
        asm volatile("s_barrier" ::: "memory");

        // Q fragments -> registers (swizzled read)
        bf16x8 aq[2][2];
        #pragma unroll
        for (int mt = 0; mt < 2; mt++)
            #pragma unroll
            for (int ks = 0; ks < 2; ks++)
                aq[mt][ks] = *(const bf16x8*)&sQP[(wave * 32 + mt * 16 + ln) * 64 +
                                                  (((ks * 4 + quad) ^ (ln & 7)) * 8)];
        asm volatile("s_waitcnt lgkmcnt(0)" ::: "memory");
        asm volatile("s_barrier" ::: "memory");   // sQP now reusable as P

        floatx4 Oacc[2][4];
        float m_run[2][4], l_run[2][4];
        #pragma unroll
        for (int mt = 0; mt < 2; mt++)
            #pragma unroll
            for (int j = 0; j < 4; j++) { Oacc[mt][j] = z4; m_run[mt][j] = -1e30f; l_run[mt][j] = 0.f; }

        const int wave_first = q0 + wave * 32;
        const int wave_last  = wave_first + 31;

        #pragma unroll 1
        for (int t = 0; t < T; t++) {
            const int kk0 = t * 64;
            const int cur = t & 1;
            if (t + 1 < T) {  // prefetch next tile into other buffer
                const unsigned short* kg = kbase + (size_t)(kk0 + 64) * 64;
                const unsigned short* vg = vbase + (size_t)(kk0 + 64);
                load16(&sK[cur ^ 1][sseg * 512], kg);
                load16(&sK[cur ^ 1][(sseg + 1) * 512], kg + (size_t)8 * 64);
                load16(&sVt[cur ^ 1][sseg * 512], vg);
                load16(&sVt[cur ^ 1][(sseg + 1) * 512], vg + (size_t)8 * 2048);
                asm volatile("s_waitcnt vmcnt(4)" ::: "memory");  // wait PREVIOUS iter's loads
            } else {
                asm volatile("s_waitcnt vmcnt(0)" ::: "memory");
            }
            asm volatile("s_barrier" ::: "memory");   // buf[cur] valid for all waves

            if (kk0 <= wave_last) {  // wave-uniform: skip fully-masked tiles
                // S = Q K^T
                floatx4 Sc[2][4];
                #pragma unroll
                for (int mt = 0; mt < 2; mt++)
                    #pragma unroll
                    for (int nt = 0; nt < 4; nt++) Sc[mt][nt] = z4;
                #pragma unroll
                for (int ks = 0; ks < 2; ks++) {
                    #pragma unroll
                    for (int nt = 0; nt < 4; nt++) {
                        bf16x8 bk = *(const bf16x8*)&sK[cur][(nt * 16 + ln) * 64 +
                                                             (((ks * 4 + quad) ^ (ln & 7)) * 8)];
                        #pragma unroll
                        for (int mt = 0; mt < 2; mt++)
                            Sc[mt][nt] = __builtin_amdgcn_mfma_f32_16x16x32_bf16(aq[mt][ks], bk, Sc[mt][nt], 0, 0, 0);
                    }
                }
                // scale + causal mask
                const bool diag = (kk0 + 63 > wave_first);
                #pragma unroll
                for (int mt = 0; mt < 2; mt++)
                    #pragma unroll
                    for (int nt = 0; nt < 4; nt++)
                        #pragma unroll
                        for (int r = 0; r < 4; r++) {
                            float v = Sc[mt][nt][r] * 0.125f;
                            if (diag) {
                                int rowg = wave_first + mt * 16 + quad * 4 + r;
                                int colg = kk0 + nt * 16 + ln;
                                if (colg > rowg) v = -1e30f;
                            }
                            Sc[mt][nt][r] = v;
                        }
                // online softmax (row spread across 16 lanes of a quad)
                float alpha[2][4];
                #pragma unroll
                for (int mt = 0; mt < 2; mt++)
                    #pragma unroll
                    for (int r = 0; r < 4; r++) {
                        float mx = fmaxf(fmaxf(Sc[mt][0][r], Sc[mt][1][r]), fmaxf(Sc[mt][2][r], Sc[mt][3][r]));
                        #pragma unroll
                        for (int off = 1; off < 16; off <<= 1) mx = fmaxf(mx, __shfl_xor(mx, off));
                        float mnew = fmaxf(m_run[mt][r], mx);
                        alpha[mt][r] = __expf(m_run[mt][r] - mnew);
                        m_run[mt][r] = mnew;
                    }
                #pragma unroll
                for (int mt = 0; mt < 2; mt++)
                    #pragma unroll
                    for (int r = 0; r < 4; r++) {
                        float rs = 0.f;
                        #pragma unroll
                        for (int nt = 0; nt < 4; nt++) {
                            float p = __expf(Sc[mt][nt][r] - m_run[mt][r]);
                            Sc[mt][nt][r] = p;
                            rs += p;
                        }
                        #pragma unroll
                        for (int off = 1; off < 16; off <<= 1) rs += __shfl_xor(rs, off);
                        l_run[mt][r] = l_run[mt][r] * alpha[mt][r] + rs;
                    }
                #pragma unroll
                for (int mt = 0; mt < 2; mt++)
                    #pragma unroll
                    for (int nt = 0; nt < 4; nt++)
                        #pragma unroll
                        for (int r = 0; r < 4; r++) Oacc[mt][nt][r] *= alpha[mt][r];
                // P -> per-wave LDS region (stride 72: conflict-free)
                #pragma unroll
                for (int mt = 0; mt < 2; mt++)
                    #pragma unroll
                    for (int nt = 0; nt < 4; nt++)
                        #pragma unroll
                        for (int r = 0; r < 4; r++)
                            sP[(mt * 16 + quad * 4 + r) * PSTR + nt * 16 + ln] = f2b(Sc[mt][nt][r]);
                // O += P V
                #pragma unroll
                for (int kp = 0; kp < 2; kp++) {
                    bf16x8 ap[2];
                    #pragma unroll
                    for (int mt = 0; mt < 2; mt++)
                        ap[mt] = *(const bf16x8*)&sP[(mt * 16 + ln) * PSTR + kp * 32 + quad * 8];
                    #pragma unroll
                    for (int nt = 0; nt < 4; nt++) {
                        bf16x8 bv = *(const bf16x8*)&sVt[cur][(nt * 16 + ln) * 64 +
                                                              (((kp * 4 + quad) ^ (ln & 7)) * 8)];
                        #pragma unroll
                        for (int mt = 0; mt < 2; mt++)
                            Oacc[mt][nt] = __builtin_amdgcn_mfma_f32_16x16x32_bf16(ap[mt], bv, Oacc[mt][nt], 0, 0, 0);
                    }
                }
            }
            asm volatile("s_barrier" ::: "memory");  // readers done before next overwrite
        }

        // epilogue for this phase
        #pragma unroll
        for (int mt = 0; mt < 2; mt++)
            #pragma unroll
            for (int nt = 0; nt < 4; nt++)
                #pragma unroll
                for (int r = 0; r < 4; r++) {
                    float o = Oacc[mt][nt][r] / l_run[mt][r];
                    int srow = q0 + wave * 32 + mt * 16 + quad * 4 + r;
                    size_t tok = (size_t)bb * 2048 + srow;
                    Ob[tok * 1024 + h * 64 + nt * 16 + ln] = f2b(o);
                }
    }
}

// ---------------------------------------------------------------------------
extern "C" void kernel_launch(void* const* d_in, const int* in_sizes, int n_in,
                              void* d_out, int out_size, void* d_ws, size_t ws_size,
                              hipStream_t stream) {
    const float* x          = (const float*)d_in[0];
    const float* ln_attn_w  = (const float*)d_in[1];
    const float* ln_attn_b  = (const float*)d_in[2];
    const float* attn_in_w  = (const float*)d_in[3];
    const float* attn_in_b  = (const float*)d_in[4];
    const float* attn_out_w = (const float*)d_in[5];
    const float* attn_out_b = (const float*)d_in[6];
    const float* ln1_w      = (const float*)d_in[7];
    const float* ln1_b      = (const float*)d_in[8];
    const float* ln2_w      = (const float*)d_in[9];
    const float* ln2_b      = (const float*)d_in[10];
    const float* inl_u_w    = (const float*)d_in[11];
    const float* inl_u_b    = (const float*)d_in[12];
    const float* inl_a_w    = (const float*)d_in[13];
    const float* inl_a_b    = (const float*)d_in[14];
    const float* inl_b_w    = (const float*)d_in[15];
    const float* inl_b_b    = (const float*)d_in[16];
    const float* inl_g_w    = (const float*)d_in[17];
    const float* inl_g_b    = (const float*)d_in[18];
    const float* ff1_w      = (const float*)d_in[19];
    const float* ff1_b      = (const float*)d_in[20];
    const float* ff2_w      = (const float*)d_in[21];
    const float* ff2_b      = (const float*)d_in[22];
    float* out = (float*)d_out;

    char* ws = (char*)d_ws;
    unsigned short* Wqkv  = (unsigned short*)(ws);
    unsigned short* Wout  = (unsigned short*)(ws + 6291456);
    unsigned short* Winl  = (unsigned short*)(ws + 8388608);
    unsigned short* Wff1  = (unsigned short*)(ws + 16777216);
    unsigned short* Wff2  = (unsigned short*)(ws + 25165824);
    unsigned short* xnb   = (unsigned short*)(ws + 33554432);   // 16MB: xn, later h
    unsigned short* qb    = (unsigned short*)(ws + 50331648);   // 16MB
    unsigned short* kb    = (unsigned short*)(ws + 67108864);   // 16MB
    unsigned short* vtb   = (unsigned short*)(ws + 83886080);   // 16MB
    unsigned short* attnb = (unsigned short*)(ws + 100663296);  // 16MB
    unsigned short* ctxb  = (unsigned short*)(ws + 117440512);  // 16MB
    float*          xs    = (float*)(ws + 134217728);           // 32MB
    float*          bias4 = (float*)(ws + 167772160);           // 16KB
    unsigned short* uabg  = (unsigned short*)(ws + 50331648);   // 64MB, reuses q/k/vt/attn
    unsigned short* ff1b  = (unsigned short*)(ws + 50331648);   // 64MB, reuses uabg

    // 1. weight conversion (weights restored before every call)
    cvt_kernel<<<3072, 256, 0, stream>>>(attn_in_w, Wqkv, 786432);
    cvt_kernel<<<1024, 256, 0, stream>>>(attn_out_w, Wout, 262144);
    cvt_kernel<<<1024, 256, 0, stream>>>(inl_u_w, Winl + 0, 262144);
    cvt_kernel<<<1024, 256, 0, stream>>>(inl_a_w, Winl + 1048576, 262144);
    cvt_kernel<<<1024, 256, 0, stream>>>(inl_b_w, Winl + 2097152, 262144);
    cvt_kernel<<<1024, 256, 0, stream>>>(inl_g_w, Winl + 3145728, 262144);
    cvt_kernel<<<4096, 256, 0, stream>>>(ff1_w, Wff1, 1048576);
    cvt_kernel<<<4096, 256, 0, stream>>>(ff2_w, Wff2, 1048576);
    catbias_kernel<<<16, 256, 0, stream>>>(inl_u_b, inl_a_b, inl_b_b, inl_g_b, bias4);

    // 2. xn = LN(x)
    ln_kernel<<<8192, 256, 0, stream>>>(x, ln_attn_w, ln_attn_b, xnb, nullptr);
    // 3. qkv projection, scattered into per-head q/k/v^T
    gemm_bt<0><<<dim3(24, 64), 256, 0, stream>>>(xnb, Wqkv, attn_in_b, 1024, qb, kb, vtb, nullptr, nullptr);
    // 4. causal flash attention (balanced pairs)
    attn_kernel<<<dim3(8, 64), 256, 0, stream>>>(qb, kb, vtb, attnb);
    // 5. out-projection: ctx (bf16) + x1 = x + ctx -> d_out
    gemm_bt<1><<<dim3(8, 64), 256, 0, stream>>>(attnb, Wout, attn_out_b, 1024, ctxb, nullptr, nullptr, out, x);
    // 6. xs0 = LN(x1)
    ln_kernel<<<8192, 256, 0, stream>>>(out, ln1_w, ln1_b, nullptr, xs);
    // 7. fused INL controllers: u | sigmoid | softplus | sigmoid
    gemm_bt<2><<<dim3(32, 64), 256, 0, stream>>>(ctxb, Winl, bias4, 1024, uabg, nullptr, nullptr, nullptr, nullptr);
    // 8. integrator: x2 = x1 + xs(5 steps) -> d_out
    integrator_kernel<<<8192, 256, 0, stream>>>(xs, uabg, out);
    // 9. h = LN(x2)
    ln_kernel<<<8192, 256, 0, stream>>>(out, ln2_w, ln2_b, xnb, nullptr);
    // 10. FF1 + exact GELU
    gemm_bt<3><<<dim3(32, 64), 256, 0, stream>>>(xnb, Wff1, ff1_b, 1024, ff1b, nullptr, nullptr, nullptr, nullptr);
    // 11. FF2 + residual accumulate -> d_out
    gemm_bt<4><<<dim3(8, 64), 256, 0, stream>>>(ff1b, Wff2, ff2_b, 4096, nullptr, nullptr, nullptr, out, nullptr);
}

// Round 4
// 890.285 us; speedup vs baseline: 1.1977x; 1.0282x over previous
//
#include <hip/hip_runtime.h>
#include <cstdint>
#include <cmath>

typedef __attribute__((ext_vector_type(4))) float floatx4;
typedef __attribute__((ext_vector_type(8))) __bf16 bf16x8;
typedef __attribute__((ext_vector_type(4))) unsigned short ushort4v;

#define DEVI static __device__ __forceinline__

DEVI unsigned short f2b(float f) {
    unsigned x = __float_as_uint(f);
    return (unsigned short)((x + 0x7fffu + ((x >> 16) & 1u)) >> 16);
}
DEVI float b2f(unsigned short u) { return __uint_as_float(((unsigned)u) << 16); }

// async global->LDS, 16B per lane; LDS dest is wave-uniform base + lane*16
DEVI void load16(void* lds, const void* g) {
    __builtin_amdgcn_global_load_lds(
        (__attribute__((address_space(1))) void*)(const_cast<void*>(g)),
        (__attribute__((address_space(3))) void*)lds, 16, 0, 0);
}

// ---------------------------------------------------------------------------
// fp32 -> bf16 convert (vector x4)
// ---------------------------------------------------------------------------
__global__ __launch_bounds__(256) void cvt_kernel(const float* __restrict__ src,
                                                  unsigned short* __restrict__ dst, int n4) {
    int i = blockIdx.x * 256 + threadIdx.x;
    if (i >= n4) return;
    floatx4 v = ((const floatx4*)src)[i];
    ushort4v o;
    o[0] = f2b(v[0]); o[1] = f2b(v[1]); o[2] = f2b(v[2]); o[3] = f2b(v[3]);
    ((ushort4v*)dst)[i] = o;
}

__global__ __launch_bounds__(256) void catbias_kernel(const float* __restrict__ a,
                                                      const float* __restrict__ b,
                                                      const float* __restrict__ c,
                                                      const float* __restrict__ d,
                                                      float* __restrict__ o) {
    int i = blockIdx.x * 256 + threadIdx.x;   // 4096 total
    int p = i >> 10, j = i & 1023;
    float v = (p == 0) ? a[j] : (p == 1) ? b[j] : (p == 2) ? c[j] : d[j];
    o[i] = v;
}

// ---------------------------------------------------------------------------
// LayerNorm over D=1024: one block per row, optional bf16 and fp32 outputs
// ---------------------------------------------------------------------------
__global__ __launch_bounds__(256) void ln_kernel(const float* __restrict__ in,
                                                 const float* __restrict__ w,
                                                 const float* __restrict__ b,
                                                 unsigned short* __restrict__ obf,
                                                 float* __restrict__ of) {
    const int row = blockIdx.x, tid = threadIdx.x;
    const floatx4* pr = (const floatx4*)(in + (size_t)row * 1024);
    floatx4 v = pr[tid];
    float s  = v[0] + v[1] + v[2] + v[3];
    float ss = v[0]*v[0] + v[1]*v[1] + v[2]*v[2] + v[3]*v[3];
    #pragma unroll
    for (int o = 32; o >= 1; o >>= 1) { s += __shfl_xor(s, o); ss += __shfl_xor(ss, o); }
    __shared__ float red[8];
    int wv = tid >> 6, lane = tid & 63;
    if (lane == 0) { red[wv] = s; red[4 + wv] = ss; }
    __syncthreads();
    s  = red[0] + red[1] + red[2] + red[3];
    ss = red[4] + red[5] + red[6] + red[7];
    float mu  = s * (1.0f / 1024.0f);
    float var = ss * (1.0f / 1024.0f) - mu * mu;
    float rstd = rsqrtf(var + 1e-5f);
    floatx4 wv4 = ((const floatx4*)w)[tid];
    floatx4 bv4 = ((const floatx4*)b)[tid];
    floatx4 o;
    #pragma unroll
    for (int c = 0; c < 4; c++) o[c] = (v[c] - mu) * rstd * wv4[c] + bv4[c];
    if (obf) {
        ushort4v t;
        t[0] = f2b(o[0]); t[1] = f2b(o[1]); t[2] = f2b(o[2]); t[3] = f2b(o[3]);
        ((ushort4v*)(obf + (size_t)row * 1024))[tid] = t;
    }
    if (of) ((floatx4*)(of + (size_t)row * 1024))[tid] = o;
}

// ---------------------------------------------------------------------------
// INL integrator: 5 explicit steps in registers, then x2 = x1 + xs -> d_out
// ---------------------------------------------------------------------------
__global__ __launch_bounds__(256) void integrator_kernel(const float* __restrict__ xs0,
                                                         const unsigned short* __restrict__ uabg,
                                                         float* __restrict__ xio) {
    size_t i = (size_t)blockIdx.x * 256 + threadIdx.x;  // group of 4 elems
    size_t tok = i >> 8;
    int grp = (int)(i & 255) * 4;
    const unsigned short* ubase = uabg + tok * 4096 + grp;
    ushort4v uu = *(const ushort4v*)(ubase);
    ushort4v aa = *(const ushort4v*)(ubase + 1024);
    ushort4v bb = *(const ushort4v*)(ubase + 2048);
    ushort4v gg = *(const ushort4v*)(ubase + 3072);
    floatx4 xsv = ((const floatx4*)xs0)[i];
    floatx4 x1  = ((const floatx4*)xio)[i];
    floatx4 res;
    #pragma unroll
    for (int c = 0; c < 4; c++) {
        float u = b2f(uu[c]), a = b2f(aa[c]), bt = b2f(bb[c]), g = b2f(gg[c]);
        float xs = xsv[c], vs = 0.f;
        #pragma unroll
        for (int t = 0; t < 5; t++) {
            vs += 0.1f * (-a * xs - bt * vs + u);
            xs += 0.1f * g * vs;
        }
        res[c] = x1[c] + xs;
    }
    ((floatx4*)xio)[i] = res;
}

// ---------------------------------------------------------------------------
// bf16 GEMM v2: C[M,N] = A[M,K] @ W[N,K]^T (+bias) with fused epilogues.
// 128x128 tile, BK=32, 4 waves (2x2 of 64x64), 16x16x32 MFMA.
//  - double-buffered LDS staging (2 x 16 KB) with raw-barrier pipeline:
//    prefetch next tile, s_waitcnt vmcnt(4) (previous iter's loads only,
//    never vmcnt(0) in steady state), s_barrier, compute, s_barrier.
//  - XOR granule swizzle on the GLOBAL side of global_load_lds so the
//    ds_read_b128 fragment reads are max-2-way on banks (free, m136).
// EPI: 0=QKV scatter  1=out-proj(+residual,+ctx)  2=INL activations
//      3=FF1 GELU     4=FF2 accumulate into d_out
// ---------------------------------------------------------------------------
template <int EPI>
__global__ __launch_bounds__(256) void gemm_bt(const unsigned short* __restrict__ A,
                                               const unsigned short* __restrict__ W,
                                               const float* __restrict__ bias, int K,
                                               unsigned short* __restrict__ ob0,
                                               unsigned short* __restrict__ ob1,
                                               unsigned short* __restrict__ ob2,
                                               float* __restrict__ of0,
                                               const float* __restrict__ xres) {
    __shared__ unsigned short sA[2][128 * 32];
    __shared__ unsigned short sB[2][128 * 32];
    const int tid = threadIdx.x;
    const int wave = tid >> 6, lane = tid & 63;
    const int ln = lane & 15, quad = lane >> 4;
    const size_t m0 = (size_t)blockIdx.y * 128;
    const int n0 = blockIdx.x * 128;
    const int wm = (wave >> 1) * 64, wn = (wave & 1) * 64;

    const floatx4 z4 = {0.f, 0.f, 0.f, 0.f};
    floatx4 acc[4][4];
    #pragma unroll
    for (int mt = 0; mt < 4; mt++)
        #pragma unroll
        for (int nt = 0; nt < 4; nt++) acc[mt][nt] = z4;

    // staging: 16 segs of 16 rows (1 KB each); wave w stages segs {w, w+4}
    // of both A and B. Global granule is XOR-swizzled by row&3 so that the
    // fragment ds_read_b128 at (row, quad^(row&3)) is bank-conflict-free.
    const int r16 = lane >> 2;               // row within 16-row seg
    const int gsw = ((lane & 3) ^ (r16 & 3)) * 8;   // swizzled granule col (elems)
    const int arow = wave * 16 + r16;
    const unsigned short* gA = A + (m0 + (size_t)arow) * K + gsw;
    const unsigned short* gB = W + ((size_t)(n0 + arow)) * K + gsw;
    const size_t rs64 = (size_t)64 * K;
    const int so = wave * 512;               // seg LDS offset (ushorts)

    // prologue: tile 0 -> buf 0
    load16(&sA[0][so], gA);
    load16(&sA[0][so + 2048], gA + rs64);
    load16(&sB[0][so], gB);
    load16(&sB[0][so + 2048], gB + rs64);

    const int T = K >> 5;
    const int swr = (quad ^ (ln & 3)) * 8;   // fragment read col (elems)

    #pragma unroll 1
    for (int t = 0; t < T; t++) {
        const int cur = t & 1;
        if (t + 1 < T) {
            const int k = (t + 1) * 32;
            load16(&sA[cur ^ 1][so], gA + k);
            load16(&sA[cur ^ 1][so + 2048], gA + rs64 + k);
            load16(&sB[cur ^ 1][so], gB + k);
            load16(&sB[cur ^ 1][so + 2048], gB + rs64 + k);
            asm volatile("s_waitcnt vmcnt(4)" ::: "memory");  // previous iter's loads
        } else {
            asm volatile("s_waitcnt vmcnt(0)" ::: "memory");
        }
        asm volatile("s_barrier" ::: "memory");   // buf[cur] valid for all waves

        bf16x8 af[4], bfr[4];
        #pragma unroll
        for (int mt = 0; mt < 4; mt++)
            af[mt] = *(const bf16x8*)&sA[cur][(wm + mt * 16 + ln) * 32 + swr];
        #pragma unroll
        for (int nt = 0; nt < 4; nt++)
            bfr[nt] = *(const bf16x8*)&sB[cur][(wn + nt * 16 + ln) * 32 + swr];
        #pragma unroll
        for (int mt = 0; mt < 4; mt++)
            #pragma unroll
            for (int nt = 0; nt < 4; nt++)
                acc[mt][nt] = __builtin_amdgcn_mfma_f32_16x16x32_bf16(af[mt], bfr[nt], acc[mt][nt], 0, 0, 0);

        asm volatile("s_waitcnt lgkmcnt(0)" ::: "memory");  // frag reads done
        asm volatile("s_barrier" ::: "memory");   // before buf[cur] is overwritten
    }

    // epilogue: C/D layout col=lane&15, row=(lane>>4)*4+reg  [verified m89/m91]
    const size_t rowb = m0 + wm + quad * 4;
    const int colb = n0 + wn + ln;
    #pragma unroll
    for (int mt = 0; mt < 4; mt++) {
        #pragma unroll
        for (int nt = 0; nt < 4; nt++) {
            const int n = colb + nt * 16;
            const float bs = bias[n];
            #pragma unroll
            for (int r = 0; r < 4; r++) {
                const size_t row = rowb + mt * 16 + r;
                float c = acc[mt][nt][r] + bs;
                if constexpr (EPI == 0) {
                    int sect = n >> 10, d1 = n & 1023, h = d1 >> 6, d = d1 & 63;
                    int bb = (int)(row >> 11), s = (int)(row & 2047);
                    size_t bh = (size_t)(bb * 16 + h);
                    if (sect == 0)      ob0[(bh * 2048 + s) * 64 + d] = f2b(c);
                    else if (sect == 1) ob1[(bh * 2048 + s) * 64 + d] = f2b(c);
                    else                ob2[(bh * 64 + d) * 2048 + s] = f2b(c);  // V^T
                } else if constexpr (EPI == 1) {
                    size_t idx = row * 1024 + n;
                    ob0[idx] = f2b(c);                 // ctx (pre-residual) for INL
                    of0[idx] = xres[idx] + c;          // x1 = x + attn_out
                } else if constexpr (EPI == 2) {
                    int p = n >> 10;
                    float v;
                    if (p == 0)       v = c;                                            // u
                    else if (p == 2)  v = fmaxf(c, 0.f) + log1pf(__expf(-fabsf(c)));    // softplus
                    else              v = 1.f / (1.f + __expf(-c));                     // sigmoid
                    ob0[row * 4096 + n] = f2b(v);
                } else if constexpr (EPI == 3) {
                    float v = 0.5f * c * (1.f + erff(c * 0.70710678118654752f));        // exact GELU
                    ob0[row * 4096 + n] = f2b(v);
                } else {
                    size_t idx = row * 1024 + n;
                    of0[idx] += c;                     // final residual accumulate
                }
            }
        }
    }
}

// ---------------------------------------------------------------------------
// Flash causal attention v3 (unchanged from R3).
// ---------------------------------------------------------------------------
#define PSTR 72
__global__ __launch_bounds__(256, 3) void attn_kernel(const unsigned short* __restrict__ Qb,
                                                      const unsigned short* __restrict__ Kb,
                                                      const unsigned short* __restrict__ Vtb,
                                                      unsigned short* __restrict__ Ob) {
    __shared__ unsigned short sK[2][64 * 64];
    __shared__ unsigned short sVt[2][64 * 64];
    __shared__ unsigned short sQP[128 * PSTR];
    const int pr = blockIdx.x;   // pair index 0..7
    const int bh = blockIdx.y;
    const int tid = threadIdx.x, wave = tid >> 6, lane = tid & 63;
    const int ln = lane & 15, quad = lane >> 4;
    const unsigned short* Q  = Qb  + (size_t)bh * 2048 * 64;
    const unsigned short* Kp = Kb  + (size_t)bh * 2048 * 64;
    const unsigned short* Vt = Vtb + (size_t)bh * 64 * 2048;

    const int rl  = lane >> 3;                    // row-in-seg 0..7
    const int gsw = (((lane & 7) ^ rl)) * 8;      // swizzled 16B-granule col (ushorts)
    const int sseg = wave * 2;
    const unsigned short* kbase = Kp + (size_t)(sseg * 8 + rl) * 64 + gsw;
    const unsigned short* vbase = Vt + (size_t)(sseg * 8 + rl) * 2048 + gsw;
    unsigned short* sP = &sQP[wave * 32 * PSTR];  // per-wave P region
    const int bb = bh >> 4, h = bh & 15;
    const floatx4 z4 = {0.f, 0.f, 0.f, 0.f};

    #pragma unroll 1
    for (int phase = 0; phase < 2; phase++) {
        const int qt = phase ? pr : (15 - pr);    // long phase first
        const int q0 = qt * 128;
        const int T = 2 * qt + 2;

        // stage Q (swizzled, stride-64 into sQP) + prefetch K/V tile 0
        #pragma unroll
        for (int i = 0; i < 4; i++) {
            int s = wave * 4 + i;
            load16(&sQP[s * 512], Q + (size_t)(q0 + s * 8 + rl) * 64 + gsw);
        }
        load16(&sK[0][sseg * 512], kbase);
        load16(&sK[0][(sseg + 1) * 512], kbase + (size_t)8 * 64);
        load16(&sVt[0][sseg * 512], vbase);
        load16(&sVt[0][(sseg + 1) * 512], vbase + (size_t)8 * 2048);
        asm volatile("s_waitcnt vmcnt(0)" ::: "memory");
        asm volatile("s_barrier" ::: "memory");

        // Q fragments -> registers (swizzled read)
        bf16x8 aq[2][2];
        #pragma unroll
        for (int mt = 0; mt < 2; mt++)
            #pragma unroll
            for (int ks = 0; ks < 2; ks++)
                aq[mt][ks] = *(const bf16x8*)&sQP[(wave * 32 + mt * 16 + ln) * 64 +
                                                  (((ks * 4 + quad) ^ (ln & 7)) * 8)];
        asm volatile("s_waitcnt lgkmcnt(0)" ::: "memory");
        asm volatile("s_barrier" ::: "memory");   // sQP now reusable as P

        floatx4 Oacc[2][4];
        float m_run[2][4], l_run[2][4];
        #pragma unroll
        for (int mt = 0; mt < 2; mt++)
            #pragma unroll
            for (int j = 0; j < 4; j++) { Oacc[mt][j] = z4; m_run[mt][j] = -1e30f; l_run[mt][j] = 0.f; }

        const int wave_first = q0 + wave * 32;
        const int wave_last  = wave_first + 31;

        #pragma unroll 1
        for (int t = 0; t < T; t++) {
            const int kk0 = t * 64;
            const int cur = t & 1;
            if (t + 1 < T) {  // prefetch next tile into other buffer
                const unsigned short* kg = kbase + (size_t)(kk0 + 64) * 64;
                const unsigned short* vg = vbase + (size_t)(kk0 + 64);
                load16(&sK[cur ^ 1][sseg * 512], kg);
                load16(&sK[cur ^ 1][(sseg + 1) * 512], kg + (size_t)8 * 64);
                load16(&sVt[cur ^ 1][sseg * 512], vg);
                load16(&sVt[cur ^ 1][(sseg + 1) * 512], vg + (size_t)8 * 2048);
                asm volatile("s_waitcnt vmcnt(4)" ::: "memory");  // wait PREVIOUS iter's loads
            } else {
                asm volatile("s_waitcnt vmcnt(0)" ::: "memory");
            }
            asm volatile("s_barrier" ::: "memory");   // buf[cur] valid for all waves

            if (kk0 <= wave_last) {  // wave-uniform: skip fully-masked tiles
                // S = Q K^T
                floatx4 Sc[2][4];
                #pragma unroll
                for (int mt = 0; mt < 2; mt++)
                    #pragma unroll
                    for (int nt = 0; nt < 4; nt++) Sc[mt][nt] = z4;
                #pragma unroll
                for (int ks = 0; ks < 2; ks++) {
                    #pragma unroll
                    for (int nt = 0; nt < 4; nt++) {
                        bf16x8 bk = *(const bf16x8*)&sK[cur][(nt * 16 + ln) * 64 +
                                                             (((ks * 4 + quad) ^ (ln & 7)) * 8)];
                        #pragma unroll
                        for (int mt = 0; mt < 2; mt++)
                            Sc[mt][nt] = __builtin_amdgcn_mfma_f32_16x16x32_bf16(aq[mt][ks], bk, Sc[mt][nt], 0, 0, 0);
                    }
                }
                // scale + causal mask
                const bool diag = (kk0 + 63 > wave_first);
                #pragma unroll
                for (int mt = 0; mt < 2; mt++)
                    #pragma unroll
                    for (int nt = 0; nt < 4; nt++)
                        #pragma unroll
                        for (int r = 0; r < 4; r++) {
                            float v = Sc[mt][nt][r] * 0.125f;
                            if (diag) {
                                int rowg = wave_first + mt * 16 + quad * 4 + r;
                                int colg = kk0 + nt * 16 + ln;
                                if (colg > rowg) v = -1e30f;
                            }
                            Sc[mt][nt][r] = v;
                        }
                // online softmax (row spread across 16 lanes of a quad)
                float alpha[2][4];
                #pragma unroll
                for (int mt = 0; mt < 2; mt++)
                    #pragma unroll
                    for (int r = 0; r < 4; r++) {
                        float mx = fmaxf(fmaxf(Sc[mt][0][r], Sc[mt][1][r]), fmaxf(Sc[mt][2][r], Sc[mt][3][r]));
                        #pragma unroll
                        for (int off = 1; off < 16; off <<= 1) mx = fmaxf(mx, __shfl_xor(mx, off));
                        float mnew = fmaxf(m_run[mt][r], mx);
                        alpha[mt][r] = __expf(m_run[mt][r] - mnew);
                        m_run[mt][r] = mnew;
                    }
                #pragma unroll
                for (int mt = 0; mt < 2; mt++)
                    #pragma unroll
                    for (int r = 0; r < 4; r++) {
                        float rs = 0.f;
                        #pragma unroll
                        for (int nt = 0; nt < 4; nt++) {
                            float p = __expf(Sc[mt][nt][r] - m_run[mt][r]);
                            Sc[mt][nt][r] = p;
                            rs += p;
                        }
                        #pragma unroll
                        for (int off = 1; off < 16; off <<= 1) rs += __shfl_xor(rs, off);
                        l_run[mt][r] = l_run[mt][r] * alpha[mt][r] + rs;
                    }
                #pragma unroll
                for (int mt = 0; mt < 2; mt++)
                    #pragma unroll
                    for (int nt = 0; nt < 4; nt++)
                        #pragma unroll
                        for (int r = 0; r < 4; r++) Oacc[mt][nt][r] *= alpha[mt][r];
                // P -> per-wave LDS region (stride 72: conflict-free)
                #pragma unroll
                for (int mt = 0; mt < 2; mt++)
                    #pragma unroll
                    for (int nt = 0; nt < 4; nt++)
                        #pragma unroll
                        for (int r = 0; r < 4; r++)
                            sP[(mt * 16 + quad * 4 + r) * PSTR + nt * 16 + ln] = f2b(Sc[mt][nt][r]);
                // O += P V
                #pragma unroll
                for (int kp = 0; kp < 2; kp++) {
                    bf16x8 ap[2];
                    #pragma unroll
                    for (int mt = 0; mt < 2; mt++)
                        ap[mt] = *(const bf16x8*)&sP[(mt * 16 + ln) * PSTR + kp * 32 + quad * 8];
                    #pragma unroll
                    for (int nt = 0; nt < 4; nt++) {
                        bf16x8 bv = *(const bf16x8*)&sVt[cur][(nt * 16 + ln) * 64 +
                                                              (((kp * 4 + quad) ^ (ln & 7)) * 8)];
                        #pragma unroll
                        for (int mt = 0; mt < 2; mt++)
                            Oacc[mt][nt] = __builtin_amdgcn_mfma_f32_16x16x32_bf16(ap[mt], bv, Oacc[mt][nt], 0, 0, 0);
                    }
                }
            }
            asm volatile("s_barrier" ::: "memory");  // readers done before next overwrite
        }

        // epilogue for this phase
        #pragma unroll
        for (int mt = 0; mt < 2; mt++)
            #pragma unroll
            for (int nt = 0; nt < 4; nt++)
                #pragma unroll
                for (int r = 0; r < 4; r++) {
                    float o = Oacc[mt][nt][r] / l_run[mt][r];
                    int srow = q0 + wave * 32 + mt * 16 + quad * 4 + r;
                    size_t tok = (size_t)bb * 2048 + srow;
                    Ob[tok * 1024 + h * 64 + nt * 16 + ln] = f2b(o);
                }
    }
}

// ---------------------------------------------------------------------------
extern "C" void kernel_launch(void* const* d_in, const int* in_sizes, int n_in,
                              void* d_out, int out_size, void* d_ws, size_t ws_size,
                              hipStream_t stream) {
    const float* x          = (const float*)d_in[0];
    const float* ln_attn_w  = (const float*)d_in[1];
    const float* ln_attn_b  = (const float*)d_in[2];
    const float* attn_in_w  = (const float*)d_in[3];
    const float* attn_in_b  = (const float*)d_in[4];
    const float* attn_out_w = (const float*)d_in[5];
    const float* attn_out_b = (const float*)d_in[6];
    const float* ln1_w      = (const float*)d_in[7];
    const float* ln1_b      = (const float*)d_in[8];
    const float* ln2_w      = (const float*)d_in[9];
    const float* ln2_b      = (const float*)d_in[10];
    const float* inl_u_w    = (const float*)d_in[11];
    const float* inl_u_b    = (const float*)d_in[12];
    const float* inl_a_w    = (const float*)d_in[13];
    const float* inl_a_b    = (const float*)d_in[14];
    const float* inl_b_w    = (const float*)d_in[15];
    const float* inl_b_b    = (const float*)d_in[16];
    const float* inl_g_w    = (const float*)d_in[17];
    const float* inl_g_b    = (const float*)d_in[18];
    const float* ff1_w      = (const float*)d_in[19];
    const float* ff1_b      = (const float*)d_in[20];
    const float* ff2_w      = (const float*)d_in[21];
    const float* ff2_b      = (const float*)d_in[22];
    float* out = (float*)d_out;

    char* ws = (char*)d_ws;
    unsigned short* Wqkv  = (unsigned short*)(ws);
    unsigned short* Wout  = (unsigned short*)(ws + 6291456);
    unsigned short* Winl  = (unsigned short*)(ws + 8388608);
    unsigned short* Wff1  = (unsigned short*)(ws + 16777216);
    unsigned short* Wff2  = (unsigned short*)(ws + 25165824);
    unsigned short* xnb   = (unsigned short*)(ws + 33554432);   // 16MB: xn, later h
    unsigned short* qb    = (unsigned short*)(ws + 50331648);   // 16MB
    unsigned short* kb    = (unsigned short*)(ws + 67108864);   // 16MB
    unsigned short* vtb   = (unsigned short*)(ws + 83886080);   // 16MB
    unsigned short* attnb = (unsigned short*)(ws + 100663296);  // 16MB
    unsigned short* ctxb  = (unsigned short*)(ws + 117440512);  // 16MB
    float*          xs    = (float*)(ws + 134217728);           // 32MB
    float*          bias4 = (float*)(ws + 167772160);           // 16KB
    unsigned short* uabg  = (unsigned short*)(ws + 50331648);   // 64MB, reuses q/k/vt/attn
    unsigned short* ff1b  = (unsigned short*)(ws + 50331648);   // 64MB, reuses uabg

    // 1. weight conversion (weights restored before every call)
    cvt_kernel<<<3072, 256, 0, stream>>>(attn_in_w, Wqkv, 786432);
    cvt_kernel<<<1024, 256, 0, stream>>>(attn_out_w, Wout, 262144);
    cvt_kernel<<<1024, 256, 0, stream>>>(inl_u_w, Winl + 0, 262144);
    cvt_kernel<<<1024, 256, 0, stream>>>(inl_a_w, Winl + 1048576, 262144);
    cvt_kernel<<<1024, 256, 0, stream>>>(inl_b_w, Winl + 2097152, 262144);
    cvt_kernel<<<1024, 256, 0, stream>>>(inl_g_w, Winl + 3145728, 262144);
    cvt_kernel<<<4096, 256, 0, stream>>>(ff1_w, Wff1, 1048576);
    cvt_kernel<<<4096, 256, 0, stream>>>(ff2_w, Wff2, 1048576);
    catbias_kernel<<<16, 256, 0, stream>>>(inl_u_b, inl_a_b, inl_b_b, inl_g_b, bias4);

    // 2. xn = LN(x)
    ln_kernel<<<8192, 256, 0, stream>>>(x, ln_attn_w, ln_attn_b, xnb, nullptr);
    // 3. qkv projection, scattered into per-head q/k/v^T
    gemm_bt<0><<<dim3(24, 64), 256, 0, stream>>>(xnb, Wqkv, attn_in_b, 1024, qb, kb, vtb, nullptr, nullptr);
    // 4. causal flash attention (balanced pairs)
    attn_kernel<<<dim3(8, 64), 256, 0, stream>>>(qb, kb, vtb, attnb);
    // 5. out-projection: ctx (bf16) + x1 = x + ctx -> d_out
    gemm_bt<1><<<dim3(8, 64), 256, 0, stream>>>(attnb, Wout, attn_out_b, 1024, ctxb, nullptr, nullptr, out, x);
    // 6. xs0 = LN(x1)
    ln_kernel<<<8192, 256, 0, stream>>>(out, ln1_w, ln1_b, nullptr, xs);
    // 7. fused INL controllers: u | sigmoid | softplus | sigmoid
    gemm_bt<2><<<dim3(32, 64), 256, 0, stream>>>(ctxb, Winl, bias4, 1024, uabg, nullptr, nullptr, nullptr, nullptr);
    // 8. integrator: x2 = x1 + xs(5 steps) -> d_out
    integrator_kernel<<<8192, 256, 0, stream>>>(xs, uabg, out);
    // 9. h = LN(x2)
    ln_kernel<<<8192, 256, 0, stream>>>(out, ln2_w, ln2_b, xnb, nullptr);
    // 10. FF1 + exact GELU
    gemm_bt<3><<<dim3(32, 64), 256, 0, stream>>>(xnb, Wff1, ff1_b, 1024, ff1b, nullptr, nullptr, nullptr, nullptr);
    // 11. FF2 + residual accumulate -> d_out
    gemm_bt<4><<<dim3(8, 64), 256, 0, stream>>>(ff1b, Wff2, ff2_b, 4096, nullptr, nullptr, nullptr, out, nullptr);
}

// Round 5
// 871.387 us; speedup vs baseline: 1.2237x; 1.0217x over previous
//
#include <hip/hip_runtime.h>
#include <cstdint>
#include <cmath>

typedef __attribute__((ext_vector_type(4))) float floatx4;
typedef __attribute__((ext_vector_type(8))) __bf16 bf16x8;
typedef __attribute__((ext_vector_type(4))) unsigned short ushort4v;

#define DEVI static __device__ __forceinline__

DEVI unsigned short f2b(float f) {
    unsigned x = __float_as_uint(f);
    return (unsigned short)((x + 0x7fffu + ((x >> 16) & 1u)) >> 16);
}
DEVI float b2f(unsigned short u) { return __uint_as_float(((unsigned)u) << 16); }

// async global->LDS, 16B per lane; LDS dest is wave-uniform base + lane*16
DEVI void load16(void* lds, const void* g) {
    __builtin_amdgcn_global_load_lds(
        (__attribute__((address_space(1))) void*)(const_cast<void*>(g)),
        (__attribute__((address_space(3))) void*)lds, 16, 0, 0);
}

// ---------------------------------------------------------------------------
// fp32 -> bf16 convert (vector x4)
// ---------------------------------------------------------------------------
__global__ __launch_bounds__(256) void cvt_kernel(const float* __restrict__ src,
                                                  unsigned short* __restrict__ dst, int n4) {
    int i = blockIdx.x * 256 + threadIdx.x;
    if (i >= n4) return;
    floatx4 v = ((const floatx4*)src)[i];
    ushort4v o;
    o[0] = f2b(v[0]); o[1] = f2b(v[1]); o[2] = f2b(v[2]); o[3] = f2b(v[3]);
    ((ushort4v*)dst)[i] = o;
}

__global__ __launch_bounds__(256) void catbias_kernel(const float* __restrict__ a,
                                                      const float* __restrict__ b,
                                                      const float* __restrict__ c,
                                                      const float* __restrict__ d,
                                                      float* __restrict__ o) {
    int i = blockIdx.x * 256 + threadIdx.x;   // 4096 total
    int p = i >> 10, j = i & 1023;
    float v = (p == 0) ? a[j] : (p == 1) ? b[j] : (p == 2) ? c[j] : d[j];
    o[i] = v;
}

// ---------------------------------------------------------------------------
// LayerNorm over D=1024: one block per row, optional bf16 and fp32 outputs
// ---------------------------------------------------------------------------
__global__ __launch_bounds__(256) void ln_kernel(const float* __restrict__ in,
                                                 const float* __restrict__ w,
                                                 const float* __restrict__ b,
                                                 unsigned short* __restrict__ obf,
                                                 float* __restrict__ of) {
    const int row = blockIdx.x, tid = threadIdx.x;
    const floatx4* pr = (const floatx4*)(in + (size_t)row * 1024);
    floatx4 v = pr[tid];
    float s  = v[0] + v[1] + v[2] + v[3];
    float ss = v[0]*v[0] + v[1]*v[1] + v[2]*v[2] + v[3]*v[3];
    #pragma unroll
    for (int o = 32; o >= 1; o >>= 1) { s += __shfl_xor(s, o); ss += __shfl_xor(ss, o); }
    __shared__ float red[8];
    int wv = tid >> 6, lane = tid & 63;
    if (lane == 0) { red[wv] = s; red[4 + wv] = ss; }
    __syncthreads();
    s  = red[0] + red[1] + red[2] + red[3];
    ss = red[4] + red[5] + red[6] + red[7];
    float mu  = s * (1.0f / 1024.0f);
    float var = ss * (1.0f / 1024.0f) - mu * mu;
    float rstd = rsqrtf(var + 1e-5f);
    floatx4 wv4 = ((const floatx4*)w)[tid];
    floatx4 bv4 = ((const floatx4*)b)[tid];
    floatx4 o;
    #pragma unroll
    for (int c = 0; c < 4; c++) o[c] = (v[c] - mu) * rstd * wv4[c] + bv4[c];
    if (obf) {
        ushort4v t;
        t[0] = f2b(o[0]); t[1] = f2b(o[1]); t[2] = f2b(o[2]); t[3] = f2b(o[3]);
        ((ushort4v*)(obf + (size_t)row * 1024))[tid] = t;
    }
    if (of) ((floatx4*)(of + (size_t)row * 1024))[tid] = o;
}

// ---------------------------------------------------------------------------
// INL integrator: 5 explicit steps in registers, then x2 = x1 + xs -> d_out
// ---------------------------------------------------------------------------
__global__ __launch_bounds__(256) void integrator_kernel(const float* __restrict__ xs0,
                                                         const unsigned short* __restrict__ uabg,
                                                         float* __restrict__ xio) {
    size_t i = (size_t)blockIdx.x * 256 + threadIdx.x;  // group of 4 elems
    size_t tok = i >> 8;
    int grp = (int)(i & 255) * 4;
    const unsigned short* ubase = uabg + tok * 4096 + grp;
    ushort4v uu = *(const ushort4v*)(ubase);
    ushort4v aa = *(const ushort4v*)(ubase + 1024);
    ushort4v bb = *(const ushort4v*)(ubase + 2048);
    ushort4v gg = *(const ushort4v*)(ubase + 3072);
    floatx4 xsv = ((const floatx4*)xs0)[i];
    floatx4 x1  = ((const floatx4*)xio)[i];
    floatx4 res;
    #pragma unroll
    for (int c = 0; c < 4; c++) {
        float u = b2f(uu[c]), a = b2f(aa[c]), bt = b2f(bb[c]), g = b2f(gg[c]);
        float xs = xsv[c], vs = 0.f;
        #pragma unroll
        for (int t = 0; t < 5; t++) {
            vs += 0.1f * (-a * xs - bt * vs + u);
            xs += 0.1f * g * vs;
        }
        res[c] = x1[c] + xs;
    }
    ((floatx4*)xio)[i] = res;
}

// ---------------------------------------------------------------------------
// bf16 GEMM v3: C[M,N] = A[M,K] @ W[N,K]^T (+bias) with fused epilogues.
// 128x128 tile, BK=32, 4 waves (2x2 of 64x64), 16x16x32 MFMA.
//  - TRIPLE-buffered LDS staging (3 x 16 KB) + register-double-buffered
//    fragments: iter t issues tile t+2 loads, waits vmcnt(4) (tile t+1
//    arrived) + lgkmcnt(0) (own frag reads drained), ONE barrier, ds_reads
//    tile t+1 frags into 'next' regs, MFMAs tile t from 'current' regs —
//    MFMAs never depend on this iteration's ds_reads.
//  - loop unrolled x2 (T always even) so frag sets have static reg names.
// EPI: 0=QKV scatter  1=out-proj(+residual,+ctx)  2=INL activations
//      3=FF1 GELU     4=FF2 accumulate into d_out
// ---------------------------------------------------------------------------
template <int EPI>
__global__ __launch_bounds__(256) void gemm_bt(const unsigned short* __restrict__ A,
                                               const unsigned short* __restrict__ W,
                                               const float* __restrict__ bias, int K,
                                               unsigned short* __restrict__ ob0,
                                               unsigned short* __restrict__ ob1,
                                               unsigned short* __restrict__ ob2,
                                               float* __restrict__ of0,
                                               const float* __restrict__ xres) {
    __shared__ unsigned short sA[3][128 * 32];
    __shared__ unsigned short sB[3][128 * 32];
    const int tid = threadIdx.x;
    const int wave = tid >> 6, lane = tid & 63;
    const int ln = lane & 15, quad = lane >> 4;
    const size_t m0 = (size_t)blockIdx.y * 128;
    const int n0 = blockIdx.x * 128;
    const int wm = (wave >> 1) * 64, wn = (wave & 1) * 64;

    const floatx4 z4 = {0.f, 0.f, 0.f, 0.f};
    floatx4 acc[4][4];
    #pragma unroll
    for (int mt = 0; mt < 4; mt++)
        #pragma unroll
        for (int nt = 0; nt < 4; nt++) acc[mt][nt] = z4;

    // staging: wave w stages A segs {w,w+4}, B segs {w,w+4} (16 rows each).
    const int r16 = lane >> 2;                      // row within 16-row seg
    const int gsw = ((lane & 3) ^ (r16 & 3)) * 8;   // swizzled granule col
    const int arow = wave * 16 + r16;
    const unsigned short* gA = A + (m0 + (size_t)arow) * K + gsw;
    const unsigned short* gB = W + ((size_t)(n0 + arow)) * K + gsw;
    const size_t rs64 = (size_t)64 * K;
    const int so = wave * 512;                      // seg LDS offset (ushorts)
    const int swr = (quad ^ (ln & 3)) * 8;          // fragment read col

    const int T = K >> 5;

    // prologue: tile 0 -> buf 0, tile 1 -> buf 1
    load16(&sA[0][so], gA);
    load16(&sA[0][so + 2048], gA + rs64);
    load16(&sB[0][so], gB);
    load16(&sB[0][so + 2048], gB + rs64);
    load16(&sA[1][so], gA + 32);
    load16(&sA[1][so + 2048], gA + rs64 + 32);
    load16(&sB[1][so], gB + 32);
    load16(&sB[1][so + 2048], gB + rs64 + 32);
    asm volatile("s_waitcnt vmcnt(4)" ::: "memory");   // tile 0 arrived
    asm volatile("s_barrier" ::: "memory");

    bf16x8 fa0[4], fb0[4], fa1[4], fb1[4];
    #pragma unroll
    for (int mt = 0; mt < 4; mt++)
        fa0[mt] = *(const bf16x8*)&sA[0][(wm + mt * 16 + ln) * 32 + swr];
    #pragma unroll
    for (int nt = 0; nt < 4; nt++)
        fb0[nt] = *(const bf16x8*)&sB[0][(wn + nt * 16 + ln) * 32 + swr];

    auto step = [&](int t, bf16x8* afc, bf16x8* bfc, bf16x8* afn, bf16x8* bfn) {
        if (t + 2 < T) {
            const int k = (t + 2) * 32;
            const int nb = (t + 2) % 3;
            load16(&sA[nb][so], gA + k);
            load16(&sA[nb][so + 2048], gA + rs64 + k);
            load16(&sB[nb][so], gB + k);
            load16(&sB[nb][so + 2048], gB + rs64 + k);
            asm volatile("s_waitcnt vmcnt(4) lgkmcnt(0)" ::: "memory");  // tile t+1 in LDS
        } else if (t + 1 < T) {
            asm volatile("s_waitcnt vmcnt(0) lgkmcnt(0)" ::: "memory");
        } else {
            asm volatile("s_waitcnt lgkmcnt(0)" ::: "memory");
        }
        asm volatile("s_barrier" ::: "memory");
        if (t + 1 < T) {
            const int nb = (t + 1) % 3;
            #pragma unroll
            for (int mt = 0; mt < 4; mt++)
                afn[mt] = *(const bf16x8*)&sA[nb][(wm + mt * 16 + ln) * 32 + swr];
            #pragma unroll
            for (int nt = 0; nt < 4; nt++)
                bfn[nt] = *(const bf16x8*)&sB[nb][(wn + nt * 16 + ln) * 32 + swr];
        }
        #pragma unroll
        for (int mt = 0; mt < 4; mt++)
            #pragma unroll
            for (int nt = 0; nt < 4; nt++)
                acc[mt][nt] = __builtin_amdgcn_mfma_f32_16x16x32_bf16(afc[mt], bfc[nt], acc[mt][nt], 0, 0, 0);
    };

    #pragma unroll 1
    for (int t = 0; t < T; t += 2) {
        step(t, fa0, fb0, fa1, fb1);
        step(t + 1, fa1, fb1, fa0, fb0);
    }

    // epilogue: C/D layout col=lane&15, row=(lane>>4)*4+reg  [verified m89/m91]
    const size_t rowb = m0 + wm + quad * 4;
    const int colb = n0 + wn + ln;
    #pragma unroll
    for (int mt = 0; mt < 4; mt++) {
        #pragma unroll
        for (int nt = 0; nt < 4; nt++) {
            const int n = colb + nt * 16;
            const float bs = bias[n];
            #pragma unroll
            for (int r = 0; r < 4; r++) {
                const size_t row = rowb + mt * 16 + r;
                float c = acc[mt][nt][r] + bs;
                if constexpr (EPI == 0) {
                    int sect = n >> 10, d1 = n & 1023, h = d1 >> 6, d = d1 & 63;
                    int bb = (int)(row >> 11), s = (int)(row & 2047);
                    size_t bh = (size_t)(bb * 16 + h);
                    if (sect == 0)      ob0[(bh * 2048 + s) * 64 + d] = f2b(c);
                    else if (sect == 1) ob1[(bh * 2048 + s) * 64 + d] = f2b(c);
                    else                ob2[(bh * 64 + d) * 2048 + s] = f2b(c);  // V^T
                } else if constexpr (EPI == 1) {
                    size_t idx = row * 1024 + n;
                    ob0[idx] = f2b(c);                 // ctx (pre-residual) for INL
                    of0[idx] = xres[idx] + c;          // x1 = x + attn_out
                } else if constexpr (EPI == 2) {
                    int p = n >> 10;
                    float v;
                    if (p == 0)       v = c;                                            // u
                    else if (p == 2)  v = fmaxf(c, 0.f) + log1pf(__expf(-fabsf(c)));    // softplus
                    else              v = 1.f / (1.f + __expf(-c));                     // sigmoid
                    ob0[row * 4096 + n] = f2b(v);
                } else if constexpr (EPI == 3) {
                    float v = 0.5f * c * (1.f + erff(c * 0.70710678118654752f));        // exact GELU
                    ob0[row * 4096 + n] = f2b(v);
                } else {
                    size_t idx = row * 1024 + n;
                    of0[idx] += c;                     // final residual accumulate
                }
            }
        }
    }
}

// ---------------------------------------------------------------------------
// Flash causal attention v3 (unchanged from R3/R4).
// ---------------------------------------------------------------------------
#define PSTR 72
__global__ __launch_bounds__(256, 3) void attn_kernel(const unsigned short* __restrict__ Qb,
                                                      const unsigned short* __restrict__ Kb,
                                                      const unsigned short* __restrict__ Vtb,
                                                      unsigned short* __restrict__ Ob) {
    __shared__ unsigned short sK[2][64 * 64];
    __shared__ unsigned short sVt[2][64 * 64];
    __shared__ unsigned short sQP[128 * PSTR];
    const int pr = blockIdx.x;   // pair index 0..7
    const int bh = blockIdx.y;
    const int tid = threadIdx.x, wave = tid >> 6, lane = tid & 63;
    const int ln = lane & 15, quad = lane >> 4;
    const unsigned short* Q  = Qb  + (size_t)bh * 2048 * 64;
    const unsigned short* Kp = Kb  + (size_t)bh * 2048 * 64;
    const unsigned short* Vt = Vtb + (size_t)bh * 64 * 2048;

    const int rl  = lane >> 3;                    // row-in-seg 0..7
    const int gsw = (((lane & 7) ^ rl)) * 8;      // swizzled 16B-granule col (ushorts)
    const int sseg = wave * 2;
    const unsigned short* kbase = Kp + (size_t)(sseg * 8 + rl) * 64 + gsw;
    const unsigned short* vbase = Vt + (size_t)(sseg * 8 + rl) * 2048 + gsw;
    unsigned short* sP = &sQP[wave * 32 * PSTR];  // per-wave P region
    const int bb = bh >> 4, h = bh & 15;
    const floatx4 z4 = {0.f, 0.f, 0.f, 0.f};

    #pragma unroll 1
    for (int phase = 0; phase < 2; phase++) {
        const int qt = phase ? pr : (15 - pr);    // long phase first
        const int q0 = qt * 128;
        const int T = 2 * qt + 2;

        // stage Q (swizzled, stride-64 into sQP) + prefetch K/V tile 0
        #pragma unroll
        for (int i = 0; i < 4; i++) {
            int s = wave * 4 + i;
            load16(&sQP[s * 512], Q + (size_t)(q0 + s * 8 + rl) * 64 + gsw);
        }
        load16(&sK[0][sseg * 512], kbase);
        load16(&sK[0][(sseg + 1) * 512], kbase + (size_t)8 * 64);
        load16(&sVt[0][sseg * 512], vbase);
        load16(&sVt[0][(sseg + 1) * 512], vbase + (size_t)8 * 2048);
        asm volatile("s_waitcnt vmcnt(0)" ::: "memory");
        asm volatile("s_barrier" ::: "memory");

        // Q fragments -> registers (swizzled read)
        bf16x8 aq[2][2];
        #pragma unroll
        for (int mt = 0; mt < 2; mt++)
            #pragma unroll
            for (int ks = 0; ks < 2; ks++)
                aq[mt][ks] = *(const bf16x8*)&sQP[(wave * 32 + mt * 16 + ln) * 64 +
                                                  (((ks * 4 + quad) ^ (ln & 7)) * 8)];
        asm volatile("s_waitcnt lgkmcnt(0)" ::: "memory");
        asm volatile("s_barrier" ::: "memory");   // sQP now reusable as P

        floatx4 Oacc[2][4];
        float m_run[2][4], l_run[2][4];
        #pragma unroll
        for (int mt = 0; mt < 2; mt++)
            #pragma unroll
            for (int j = 0; j < 4; j++) { Oacc[mt][j] = z4; m_run[mt][j] = -1e30f; l_run[mt][j] = 0.f; }

        const int wave_first = q0 + wave * 32;
        const int wave_last  = wave_first + 31;

        #pragma unroll 1
        for (int t = 0; t < T; t++) {
            const int kk0 = t * 64;
            const int cur = t & 1;
            if (t + 1 < T) {  // prefetch next tile into other buffer
                const unsigned short* kg = kbase + (size_t)(kk0 + 64) * 64;
                const unsigned short* vg = vbase + (size_t)(kk0 + 64);
                load16(&sK[cur ^ 1][sseg * 512], kg);
                load16(&sK[cur ^ 1][(sseg + 1) * 512], kg + (size_t)8 * 64);
                load16(&sVt[cur ^ 1][sseg * 512], vg);
                load16(&sVt[cur ^ 1][(sseg + 1) * 512], vg + (size_t)8 * 2048);
                asm volatile("s_waitcnt vmcnt(4)" ::: "memory");  // wait PREVIOUS iter's loads
            } else {
                asm volatile("s_waitcnt vmcnt(0)" ::: "memory");
            }
            asm volatile("s_barrier" ::: "memory");   // buf[cur] valid for all waves

            if (kk0 <= wave_last) {  // wave-uniform: skip fully-masked tiles
                // S = Q K^T
                floatx4 Sc[2][4];
                #pragma unroll
                for (int mt = 0; mt < 2; mt++)
                    #pragma unroll
                    for (int nt = 0; nt < 4; nt++) Sc[mt][nt] = z4;
                #pragma unroll
                for (int ks = 0; ks < 2; ks++) {
                    #pragma unroll
                    for (int nt = 0; nt < 4; nt++) {
                        bf16x8 bk = *(const bf16x8*)&sK[cur][(nt * 16 + ln) * 64 +
                                                             (((ks * 4 + quad) ^ (ln & 7)) * 8)];
                        #pragma unroll
                        for (int mt = 0; mt < 2; mt++)
                            Sc[mt][nt] = __builtin_amdgcn_mfma_f32_16x16x32_bf16(aq[mt][ks], bk, Sc[mt][nt], 0, 0, 0);
                    }
                }
                // scale + causal mask
                const bool diag = (kk0 + 63 > wave_first);
                #pragma unroll
                for (int mt = 0; mt < 2; mt++)
                    #pragma unroll
                    for (int nt = 0; nt < 4; nt++)
                        #pragma unroll
                        for (int r = 0; r < 4; r++) {
                            float v = Sc[mt][nt][r] * 0.125f;
                            if (diag) {
                                int rowg = wave_first + mt * 16 + quad * 4 + r;
                                int colg = kk0 + nt * 16 + ln;
                                if (colg > rowg) v = -1e30f;
                            }
                            Sc[mt][nt][r] = v;
                        }
                // online softmax (row spread across 16 lanes of a quad)
                float alpha[2][4];
                #pragma unroll
                for (int mt = 0; mt < 2; mt++)
                    #pragma unroll
                    for (int r = 0; r < 4; r++) {
                        float mx = fmaxf(fmaxf(Sc[mt][0][r], Sc[mt][1][r]), fmaxf(Sc[mt][2][r], Sc[mt][3][r]));
                        #pragma unroll
                        for (int off = 1; off < 16; off <<= 1) mx = fmaxf(mx, __shfl_xor(mx, off));
                        float mnew = fmaxf(m_run[mt][r], mx);
                        alpha[mt][r] = __expf(m_run[mt][r] - mnew);
                        m_run[mt][r] = mnew;
                    }
                #pragma unroll
                for (int mt = 0; mt < 2; mt++)
                    #pragma unroll
                    for (int r = 0; r < 4; r++) {
                        float rs = 0.f;
                        #pragma unroll
                        for (int nt = 0; nt < 4; nt++) {
                            float p = __expf(Sc[mt][nt][r] - m_run[mt][r]);
                            Sc[mt][nt][r] = p;
                            rs += p;
                        }
                        #pragma unroll
                        for (int off = 1; off < 16; off <<= 1) rs += __shfl_xor(rs, off);
                        l_run[mt][r] = l_run[mt][r] * alpha[mt][r] + rs;
                    }
                #pragma unroll
                for (int mt = 0; mt < 2; mt++)
                    #pragma unroll
                    for (int nt = 0; nt < 4; nt++)
                        #pragma unroll
                        for (int r = 0; r < 4; r++) Oacc[mt][nt][r] *= alpha[mt][r];
                // P -> per-wave LDS region (stride 72: conflict-free)
                #pragma unroll
                for (int mt = 0; mt < 2; mt++)
                    #pragma unroll
                    for (int nt = 0; nt < 4; nt++)
                        #pragma unroll
                        for (int r = 0; r < 4; r++)
                            sP[(mt * 16 + quad * 4 + r) * PSTR + nt * 16 + ln] = f2b(Sc[mt][nt][r]);
                // O += P V
                #pragma unroll
                for (int kp = 0; kp < 2; kp++) {
                    bf16x8 ap[2];
                    #pragma unroll
                    for (int mt = 0; mt < 2; mt++)
                        ap[mt] = *(const bf16x8*)&sP[(mt * 16 + ln) * PSTR + kp * 32 + quad * 8];
                    #pragma unroll
                    for (int nt = 0; nt < 4; nt++) {
                        bf16x8 bv = *(const bf16x8*)&sVt[cur][(nt * 16 + ln) * 64 +
                                                              (((kp * 4 + quad) ^ (ln & 7)) * 8)];
                        #pragma unroll
                        for (int mt = 0; mt < 2; mt++)
                            Oacc[mt][nt] = __builtin_amdgcn_mfma_f32_16x16x32_bf16(ap[mt], bv, Oacc[mt][nt], 0, 0, 0);
                    }
                }
            }
            asm volatile("s_barrier" ::: "memory");  // readers done before next overwrite
        }

        // epilogue for this phase
        #pragma unroll
        for (int mt = 0; mt < 2; mt++)
            #pragma unroll
            for (int nt = 0; nt < 4; nt++)
                #pragma unroll
                for (int r = 0; r < 4; r++) {
                    float o = Oacc[mt][nt][r] / l_run[mt][r];
                    int srow = q0 + wave * 32 + mt * 16 + quad * 4 + r;
                    size_t tok = (size_t)bb * 2048 + srow;
                    Ob[tok * 1024 + h * 64 + nt * 16 + ln] = f2b(o);
                }
    }
}

// ---------------------------------------------------------------------------
extern "C" void kernel_launch(void* const* d_in, const int* in_sizes, int n_in,
                              void* d_out, int out_size, void* d_ws, size_t ws_size,
                              hipStream_t stream) {
    const float* x          = (const float*)d_in[0];
    const float* ln_attn_w  = (const float*)d_in[1];
    const float* ln_attn_b  = (const float*)d_in[2];
    const float* attn_in_w  = (const float*)d_in[3];
    const float* attn_in_b  = (const float*)d_in[4];
    const float* attn_out_w = (const float*)d_in[5];
    const float* attn_out_b = (const float*)d_in[6];
    const float* ln1_w      = (const float*)d_in[7];
    const float* ln1_b      = (const float*)d_in[8];
    const float* ln2_w      = (const float*)d_in[9];
    const float* ln2_b      = (const float*)d_in[10];
    const float* inl_u_w    = (const float*)d_in[11];
    const float* inl_u_b    = (const float*)d_in[12];
    const float* inl_a_w    = (const float*)d_in[13];
    const float* inl_a_b    = (const float*)d_in[14];
    const float* inl_b_w    = (const float*)d_in[15];
    const float* inl_b_b    = (const float*)d_in[16];
    const float* inl_g_w    = (const float*)d_in[17];
    const float* inl_g_b    = (const float*)d_in[18];
    const float* ff1_w      = (const float*)d_in[19];
    const float* ff1_b      = (const float*)d_in[20];
    const float* ff2_w      = (const float*)d_in[21];
    const float* ff2_b      = (const float*)d_in[22];
    float* out = (float*)d_out;

    char* ws = (char*)d_ws;
    unsigned short* Wqkv  = (unsigned short*)(ws);
    unsigned short* Wout  = (unsigned short*)(ws + 6291456);
    unsigned short* Winl  = (unsigned short*)(ws + 8388608);
    unsigned short* Wff1  = (unsigned short*)(ws + 16777216);
    unsigned short* Wff2  = (unsigned short*)(ws + 25165824);
    unsigned short* xnb   = (unsigned short*)(ws + 33554432);   // 16MB: xn, later h
    unsigned short* qb    = (unsigned short*)(ws + 50331648);   // 16MB
    unsigned short* kb    = (unsigned short*)(ws + 67108864);   // 16MB
    unsigned short* vtb   = (unsigned short*)(ws + 83886080);   // 16MB
    unsigned short* attnb = (unsigned short*)(ws + 100663296);  // 16MB
    unsigned short* ctxb  = (unsigned short*)(ws + 117440512);  // 16MB
    float*          xs    = (float*)(ws + 134217728);           // 32MB
    float*          bias4 = (float*)(ws + 167772160);           // 16KB
    unsigned short* uabg  = (unsigned short*)(ws + 50331648);   // 64MB, reuses q/k/vt/attn
    unsigned short* ff1b  = (unsigned short*)(ws + 50331648);   // 64MB, reuses uabg

    // 1. weight conversion (weights restored before every call)
    cvt_kernel<<<3072, 256, 0, stream>>>(attn_in_w, Wqkv, 786432);
    cvt_kernel<<<1024, 256, 0, stream>>>(attn_out_w, Wout, 262144);
    cvt_kernel<<<1024, 256, 0, stream>>>(inl_u_w, Winl + 0, 262144);
    cvt_kernel<<<1024, 256, 0, stream>>>(inl_a_w, Winl + 1048576, 262144);
    cvt_kernel<<<1024, 256, 0, stream>>>(inl_b_w, Winl + 2097152, 262144);
    cvt_kernel<<<1024, 256, 0, stream>>>(inl_g_w, Winl + 3145728, 262144);
    cvt_kernel<<<4096, 256, 0, stream>>>(ff1_w, Wff1, 1048576);
    cvt_kernel<<<4096, 256, 0, stream>>>(ff2_w, Wff2, 1048576);
    catbias_kernel<<<16, 256, 0, stream>>>(inl_u_b, inl_a_b, inl_b_b, inl_g_b, bias4);

    // 2. xn = LN(x)
    ln_kernel<<<8192, 256, 0, stream>>>(x, ln_attn_w, ln_attn_b, xnb, nullptr);
    // 3. qkv projection, scattered into per-head q/k/v^T
    gemm_bt<0><<<dim3(24, 64), 256, 0, stream>>>(xnb, Wqkv, attn_in_b, 1024, qb, kb, vtb, nullptr, nullptr);
    // 4. causal flash attention (balanced pairs)
    attn_kernel<<<dim3(8, 64), 256, 0, stream>>>(qb, kb, vtb, attnb);
    // 5. out-projection: ctx (bf16) + x1 = x + ctx -> d_out
    gemm_bt<1><<<dim3(8, 64), 256, 0, stream>>>(attnb, Wout, attn_out_b, 1024, ctxb, nullptr, nullptr, out, x);
    // 6. xs0 = LN(x1)
    ln_kernel<<<8192, 256, 0, stream>>>(out, ln1_w, ln1_b, nullptr, xs);
    // 7. fused INL controllers: u | sigmoid | softplus | sigmoid
    gemm_bt<2><<<dim3(32, 64), 256, 0, stream>>>(ctxb, Winl, bias4, 1024, uabg, nullptr, nullptr, nullptr, nullptr);
    // 8. integrator: x2 = x1 + xs(5 steps) -> d_out
    integrator_kernel<<<8192, 256, 0, stream>>>(xs, uabg, out);
    // 9. h = LN(x2)
    ln_kernel<<<8192, 256, 0, stream>>>(out, ln2_w, ln2_b, xnb, nullptr);
    // 10. FF1 + exact GELU
    gemm_bt<3><<<dim3(32, 64), 256, 0, stream>>>(xnb, Wff1, ff1_b, 1024, ff1b, nullptr, nullptr, nullptr, nullptr);
    // 11. FF2 + residual accumulate -> d_out
    gemm_bt<4><<<dim3(8, 64), 256, 0, stream>>>(ff1b, Wff2, ff2_b, 4096, nullptr, nullptr, nullptr, out, nullptr);
}